// Round 3
// baseline (1146.426 us; speedup 1.0000x reference)
//
#include <hip/hip_runtime.h>
#include <hip/hip_fp16.h>
#include <math.h>

// ---------------------------------------------------------------------------
// R9: kill partition write-amplification + drop the src partition entirely.
// R8b counters: k_part_dst = 184 us with WRITE 504 MB for 64 MB payload (8x):
// random 4B scatter dirties a 64B line per store. Fix: LDS-staged partition --
// per 16K-edge block, histogram -> scan -> bucket-major LDS staging -> 
// positional write-out (binary search for bucket) so consecutive lanes write
// consecutive addresses. Also: out-degree now via fused global atomics on
// deg[] (4 MB, LLC-resident) inside k_part_dst; k_part_src/k_deg_src deleted.
// onorm computed+stored by k_node1.
//
// ws layout (dwords):
//   pd     [NBKT*CAP]
//   cd     [NBKT]  gsum [4G]  gcnt [G]  deg [n]   (zeroed via one memset)
//   onorm  [n]
//   starts [NBKT*2048]
//   y1     [2n]   fp8x8 per node (8 B)
//   y2     [n]    fp8x4 per node (4 B)
//   part   [4n]   fp16x8 per node (16 B), reused as fp16x4 (8 B) for agg2
// ---------------------------------------------------------------------------

#define BSHIFT 10
#define BMASK  1023u
#define NBKT   1024
#define CAP    17408u
#define SRT    ((CAP + 511) / 512)
#define NBIN   2048

#define PTH2   1024
#define EPT2   16
#define CHUNK2 (PTH2 * EPT2)   // 16384 edges / block

typedef float v2f __attribute__((ext_vector_type(2)));
typedef unsigned int u32x4 __attribute__((ext_vector_type(4)));
typedef unsigned int u32x2 __attribute__((ext_vector_type(2)));

template <bool HI>
__device__ inline v2f up8(unsigned int w) {
    return __builtin_amdgcn_cvt_pk_f32_fp8((int)w, HI);
}
__device__ inline unsigned int pk4(float a, float b, float c, float d) {
    int r = __builtin_amdgcn_cvt_pk_fp8_f32(a, b, 0, false);
    r = __builtin_amdgcn_cvt_pk_fp8_f32(c, d, r, true);
    return (unsigned int)r;
}
__device__ inline unsigned int pkh(float a, float b) {
    __half2 h = __floats2half2_rn(a, b);
    union { __half2 h; unsigned int u; } c; c.h = h; return c.u;
}
__device__ inline v2f uph(unsigned int u) {
    union { unsigned int u; __half2 h; } c; c.u = u;
    float2 f = __half22float2(c.h);
    v2f r; r.x = f.x; r.y = f.y; return r;
}
__device__ inline void acc8(float* acc, uint2 v) {
    v2f f0 = up8<false>(v.x);
    v2f f1 = up8<true>(v.x);
    v2f f2 = up8<false>(v.y);
    v2f f3 = up8<true>(v.y);
    acc[0] += f0.x; acc[1] += f0.y; acc[2] += f1.x; acc[3] += f1.y;
    acc[4] += f2.x; acc[5] += f2.y; acc[6] += f3.x; acc[7] += f3.y;
}
__device__ inline void acc4(float* acc, unsigned int q) {
    v2f f0 = up8<false>(q);
    v2f f1 = up8<true>(q);
    acc[0] += f0.x; acc[1] += f0.y; acc[2] += f1.x; acc[3] += f1.y;
}

// ---- partition dst (LDS-staged, coalesced write-out) + fused out-degree ---
__global__ __launch_bounds__(PTH2) void k_part_dst(const int* __restrict__ src,
                                                   const int* __restrict__ dst,
                                                   unsigned int* __restrict__ pd,
                                                   unsigned int* __restrict__ cur,
                                                   unsigned int* __restrict__ deg,
                                                   int n_edges) {
    __shared__ unsigned int hist[NBKT];
    __shared__ unsigned int scanA[NBKT];
    __shared__ unsigned int scanB[NBKT];
    __shared__ unsigned int gbase[NBKT];
    __shared__ unsigned int stage[CHUNK2];
    const int tid = threadIdx.x;
    const int e0 = blockIdx.x * CHUNK2;
    hist[tid] = 0;                       // PTH2 == NBKT
    __syncthreads();
    unsigned int wv[EPT2];
    unsigned int bb[EPT2];
    unsigned int rk[EPT2];
#pragma unroll
    for (int k = 0; k < EPT2; ++k) {
        int e = e0 + k * PTH2 + tid;
        bb[k] = 0xFFFFFFFFu;
        if (e < n_edges) {
            unsigned int d = (unsigned int)dst[e];
            unsigned int s = (unsigned int)src[e];
            unsigned int b = d >> BSHIFT;
            wv[k] = (s << BSHIFT) | (d & BMASK);
            bb[k] = b;
            rk[k] = atomicAdd(&hist[b], 1u);
            atomicAdd(&deg[s], 1u);      // fused out-degree (fire-and-forget)
        }
    }
    __syncthreads();
    const unsigned int cnt = hist[tid];
    scanA[tid] = cnt;
    __syncthreads();
    unsigned int* pin = scanA;
    unsigned int* pout = scanB;
    for (int off = 1; off < NBKT; off <<= 1) {
        unsigned int v = pin[tid];
        if (tid >= off) v += pin[tid - off];
        pout[tid] = v;
        __syncthreads();
        unsigned int* t = pin; pin = pout; pout = t;
    }
    // pin[b] = inclusive prefix count
    gbase[tid] = atomicAdd(&cur[tid], cnt);
    __syncthreads();
#pragma unroll
    for (int k = 0; k < EPT2; ++k) {
        if (bb[k] != 0xFFFFFFFFu) {
            unsigned int start = (bb[k] == 0) ? 0u : pin[bb[k] - 1];
            stage[start + rk[k]] = wv[k];
        }
    }
    __syncthreads();
    const unsigned int total = pin[NBKT - 1];
    for (unsigned int i = tid; i < total; i += PTH2) {
        unsigned int w = stage[i];
        unsigned int lo = 0, hi = NBKT - 1;
        while (lo < hi) {                 // first b with pin[b] > i
            unsigned int mid = (lo + hi) >> 1;
            if (pin[mid] > i) hi = mid; else lo = mid + 1;
        }
        unsigned int start = (lo == 0) ? 0u : pin[lo - 1];
        pd[lo * CAP + gbase[lo] + (i - start)] = w;
    }
}

// ---- counting sort of one bucket's edges by (dst_low, src_tile) -----------
// key = (dlow << 1) | tile, tile = bit19 of src (= bit29 of payload word).
__global__ __launch_bounds__(512) void k_sort_dst(unsigned int* __restrict__ pd,
                                                  const unsigned int* __restrict__ cur,
                                                  unsigned int* __restrict__ starts) {
    __shared__ unsigned int sA[NBIN];
    __shared__ unsigned int sB[NBIN];
    __shared__ unsigned int curs[NBIN];
    const int b = blockIdx.x, tid = threadIdx.x;
    for (int i = tid; i < NBIN; i += 512) sA[i] = 0;
    __syncthreads();
    const unsigned int n = cur[b];
    const unsigned int base = (unsigned int)b * CAP;
    unsigned int rv[SRT];
#pragma unroll
    for (int k = 0; k < SRT; ++k) {
        unsigned int i = (unsigned int)k * 512u + (unsigned int)tid;
        rv[k] = 0xFFFFFFFFu;
        if (i < n) {
            rv[k] = pd[base + i];
            unsigned int key = ((rv[k] & BMASK) << 1) | ((rv[k] >> 29) & 1u);
            atomicAdd(&sA[key], 1u);
        }
    }
    __syncthreads();
    unsigned int* pin = sA;
    unsigned int* pout = sB;
    for (int off = 1; off < NBIN; off <<= 1) {
        for (int r = tid; r < NBIN; r += 512) {
            unsigned int v = pin[r];
            if (r >= off) v += pin[r - off];
            pout[r] = v;
        }
        __syncthreads();
        unsigned int* t = pin; pin = pout; pout = t;
    }
    for (int r = tid; r < NBIN; r += 512) {
        unsigned int st = (r == 0) ? 0u : pin[r - 1];
        curs[r] = st;
        starts[(size_t)b * NBIN + r] = st;
    }
    __syncthreads();
#pragma unroll
    for (int k = 0; k < SRT; ++k) {
        if (rv[k] != 0xFFFFFFFFu) {
            unsigned int key = ((rv[k] & BMASK) << 1) | ((rv[k] >> 29) & 1u);
            unsigned int pos = atomicAdd(&curs[key], 1u);
            pd[base + pos] = rv[k];
        }
    }
}

// ---- y1 = fp8( (feat @ W1) * onorm ); also materializes onorm from deg ----
__global__ void k_node1(const float* __restrict__ feat, const float* __restrict__ W1,
                        const unsigned int* __restrict__ deg,
                        float* __restrict__ onorm, uint2* __restrict__ y1,
                        int n_nodes) {
    int i = blockIdx.x * blockDim.x + threadIdx.x;
    if (i >= n_nodes) return;
    float on = rsqrtf(fmaxf((float)deg[i], 1.0f));
    onorm[i] = on;
    const float* fr = feat + (size_t)i * 10;
    float f[10];
#pragma unroll
    for (int k = 0; k < 10; ++k) f[k] = fr[k];
    float acc[8];
#pragma unroll
    for (int j = 0; j < 8; ++j) acc[j] = 0.0f;
#pragma unroll
    for (int k = 0; k < 10; ++k)
#pragma unroll
        for (int j = 0; j < 8; ++j) acc[j] = fmaf(f[k], W1[k * 8 + j], acc[j]);
    uint2 o;
    o.x = pk4(acc[0] * on, acc[1] * on, acc[2] * on, acc[3] * on);
    o.y = pk4(acc[4] * on, acc[5] * on, acc[6] * on, acc[7] * on);
    y1[i] = o;
}

// ---- layer1 agg, tile0: y1[0 .. 2^19) gathers only -> fp16 partial --------
__global__ __launch_bounds__(1024) void k_agg1a(const unsigned int* __restrict__ pd,
                                                const unsigned int* __restrict__ starts,
                                                const uint2* __restrict__ y,
                                                u32x4* __restrict__ part, int n_nodes) {
    const int b = blockIdx.x;
    const int r = threadIdx.x;
    const int node = (b << BSHIFT) + r;
    if (node >= n_nodes) return;
    const unsigned int base = (unsigned int)b * CAP;
    const unsigned int* st = starts + ((size_t)b << 11);
    unsigned int s = st[2 * r];
    unsigned int e = st[2 * r + 1];
    float acc[8];
#pragma unroll
    for (int j = 0; j < 8; ++j) acc[j] = 0.0f;
    unsigned int i = s;
    for (; i + 4 <= e; i += 4) {
        unsigned int w0 = pd[base + i + 0];
        unsigned int w1 = pd[base + i + 1];
        unsigned int w2 = pd[base + i + 2];
        unsigned int w3 = pd[base + i + 3];
        uint2 v0 = y[w0 >> BSHIFT];
        uint2 v1 = y[w1 >> BSHIFT];
        uint2 v2 = y[w2 >> BSHIFT];
        uint2 v3 = y[w3 >> BSHIFT];
        acc8(acc, v0); acc8(acc, v1); acc8(acc, v2); acc8(acc, v3);
    }
    for (; i < e; ++i) acc8(acc, y[pd[base + i] >> BSHIFT]);
    u32x4 p;
    p.x = pkh(acc[0], acc[1]);
    p.y = pkh(acc[2], acc[3]);
    p.z = pkh(acc[4], acc[5]);
    p.w = pkh(acc[6], acc[7]);
    __builtin_nontemporal_store(p, part + node);
}

// ---- layer1 agg, tile1 + partial add + fused node2 ------------------------
__global__ __launch_bounds__(1024) void k_agg1b(const unsigned int* __restrict__ pd,
                                                const unsigned int* __restrict__ cur,
                                                const unsigned int* __restrict__ starts,
                                                const uint2* __restrict__ y,
                                                const u32x4* __restrict__ part,
                                                const float* __restrict__ b1,
                                                const float* __restrict__ W2,
                                                const float* __restrict__ onorm,
                                                unsigned int* __restrict__ y2, int n_nodes) {
    const int b = blockIdx.x;
    const int r = threadIdx.x;
    const int node = (b << BSHIFT) + r;
    if (node >= n_nodes) return;
    const unsigned int base = (unsigned int)b * CAP;
    const unsigned int* st = starts + ((size_t)b << 11);
    unsigned int s0 = st[2 * r];
    unsigned int s = st[2 * r + 1];
    unsigned int e = (r == 1023) ? cur[b] : st[2 * r + 2];
    float acc[8];
#pragma unroll
    for (int j = 0; j < 8; ++j) acc[j] = 0.0f;
    unsigned int i = s;
    for (; i + 4 <= e; i += 4) {
        unsigned int w0 = pd[base + i + 0];
        unsigned int w1 = pd[base + i + 1];
        unsigned int w2 = pd[base + i + 2];
        unsigned int w3 = pd[base + i + 3];
        uint2 v0 = y[w0 >> BSHIFT];
        uint2 v1 = y[w1 >> BSHIFT];
        uint2 v2 = y[w2 >> BSHIFT];
        uint2 v3 = y[w3 >> BSHIFT];
        acc8(acc, v0); acc8(acc, v1); acc8(acc, v2); acc8(acc, v3);
    }
    for (; i < e; ++i) acc8(acc, y[pd[base + i] >> BSHIFT]);
    u32x4 p = __builtin_nontemporal_load(part + node);
    v2f q0 = uph(p.x), q1 = uph(p.y), q2 = uph(p.z), q3 = uph(p.w);
    acc[0] += q0.x; acc[1] += q0.y; acc[2] += q1.x; acc[3] += q1.y;
    acc[4] += q2.x; acc[5] += q2.y; acc[6] += q3.x; acc[7] += q3.y;
    float inn = rsqrtf(fmaxf((float)(e - s0), 1.0f));
    float h[8];
#pragma unroll
    for (int j = 0; j < 8; ++j) h[j] = fmaxf(fmaf(acc[j], inn, b1[j]), 0.0f);
    float z[4] = {0.0f, 0.0f, 0.0f, 0.0f};
#pragma unroll
    for (int k = 0; k < 8; ++k)
#pragma unroll
        for (int j = 0; j < 4; ++j) z[j] = fmaf(h[k], W2[k * 4 + j], z[j]);
    float on = onorm[node];
    y2[node] = pk4(z[0] * on, z[1] * on, z[2] * on, z[3] * on);
}

// ---- layer2 agg, tile0 -> fp16 partial ------------------------------------
__global__ __launch_bounds__(1024) void k_agg2a(const unsigned int* __restrict__ pd,
                                                const unsigned int* __restrict__ starts,
                                                const unsigned int* __restrict__ y,
                                                u32x2* __restrict__ part, int n_nodes) {
    const int b = blockIdx.x;
    const int r = threadIdx.x;
    const int node = (b << BSHIFT) + r;
    if (node >= n_nodes) return;
    const unsigned int base = (unsigned int)b * CAP;
    const unsigned int* st = starts + ((size_t)b << 11);
    unsigned int s = st[2 * r];
    unsigned int e = st[2 * r + 1];
    float acc[4] = {0.0f, 0.0f, 0.0f, 0.0f};
    unsigned int i = s;
    for (; i + 4 <= e; i += 4) {
        unsigned int w0 = pd[base + i + 0];
        unsigned int w1 = pd[base + i + 1];
        unsigned int w2 = pd[base + i + 2];
        unsigned int w3 = pd[base + i + 3];
        unsigned int q0 = y[w0 >> BSHIFT];
        unsigned int q1 = y[w1 >> BSHIFT];
        unsigned int q2 = y[w2 >> BSHIFT];
        unsigned int q3 = y[w3 >> BSHIFT];
        acc4(acc, q0); acc4(acc, q1); acc4(acc, q2); acc4(acc, q3);
    }
    for (; i < e; ++i) acc4(acc, y[pd[base + i] >> BSHIFT]);
    u32x2 p;
    p.x = pkh(acc[0], acc[1]);
    p.y = pkh(acc[2], acc[3]);
    __builtin_nontemporal_store(p, part + node);
}

// ---- layer2 agg, tile1 + partial add + fused graph pooling ----------------
__global__ __launch_bounds__(1024) void k_agg2b(const unsigned int* __restrict__ pd,
                                                const unsigned int* __restrict__ cur,
                                                const unsigned int* __restrict__ starts,
                                                const unsigned int* __restrict__ y,
                                                const u32x2* __restrict__ part,
                                                const float* __restrict__ b2,
                                                const int* __restrict__ gid,
                                                float* __restrict__ gsum,
                                                float* __restrict__ gcnt, int n_nodes) {
    const int b = blockIdx.x;
    const int r = threadIdx.x;
    const int node = (b << BSHIFT) + r;
    const int lane = threadIdx.x & 63;
    int g = -1;
    float v0 = 0.f, v1 = 0.f, v2 = 0.f, v3 = 0.f, c = 0.f;
    if (node < n_nodes) {
        const unsigned int base = (unsigned int)b * CAP;
        const unsigned int* st = starts + ((size_t)b << 11);
        unsigned int s0 = st[2 * r];
        unsigned int s = st[2 * r + 1];
        unsigned int e = (r == 1023) ? cur[b] : st[2 * r + 2];
        float acc[4] = {0.0f, 0.0f, 0.0f, 0.0f};
        unsigned int i = s;
        for (; i + 4 <= e; i += 4) {
            unsigned int w0 = pd[base + i + 0];
            unsigned int w1 = pd[base + i + 1];
            unsigned int w2 = pd[base + i + 2];
            unsigned int w3 = pd[base + i + 3];
            unsigned int q0 = y[w0 >> BSHIFT];
            unsigned int q1 = y[w1 >> BSHIFT];
            unsigned int q2 = y[w2 >> BSHIFT];
            unsigned int q3 = y[w3 >> BSHIFT];
            acc4(acc, q0); acc4(acc, q1); acc4(acc, q2); acc4(acc, q3);
        }
        for (; i < e; ++i) acc4(acc, y[pd[base + i] >> BSHIFT]);
        u32x2 p = __builtin_nontemporal_load(part + node);
        v2f p0 = uph(p.x), p1 = uph(p.y);
        acc[0] += p0.x; acc[1] += p0.y; acc[2] += p1.x; acc[3] += p1.y;
        float inn = rsqrtf(fmaxf((float)(e - s0), 1.0f));
        v0 = fmaxf(fmaf(acc[0], inn, b2[0]), 0.0f);
        v1 = fmaxf(fmaf(acc[1], inn, b2[1]), 0.0f);
        v2 = fmaxf(fmaf(acc[2], inn, b2[2]), 0.0f);
        v3 = fmaxf(fmaf(acc[3], inn, b2[3]), 0.0f);
        c = 1.0f;
        g = gid[node];
    }
#pragma unroll
    for (int sft = 1; sft < 64; sft <<= 1) {
        int go   = __shfl_down(g, sft);
        float t0 = __shfl_down(v0, sft);
        float t1 = __shfl_down(v1, sft);
        float t2 = __shfl_down(v2, sft);
        float t3 = __shfl_down(v3, sft);
        float tc = __shfl_down(c, sft);
        if (lane + sft < 64 && go == g) {
            v0 += t0; v1 += t1; v2 += t2; v3 += t3; c += tc;
        }
    }
    int gp = __shfl_up(g, 1);
    bool head = (lane == 0) || (gp != g);
    if (g >= 0 && head) {
        unsafeAtomicAdd(&gsum[g * 4 + 0], v0);
        unsafeAtomicAdd(&gsum[g * 4 + 1], v1);
        unsafeAtomicAdd(&gsum[g * 4 + 2], v2);
        unsafeAtomicAdd(&gsum[g * 4 + 3], v3);
        unsafeAtomicAdd(&gcnt[g], c);
    }
}

__global__ void k_final(const float* __restrict__ gsum, const float* __restrict__ gcnt,
                        const float* __restrict__ Wo, const float* __restrict__ bo,
                        float* __restrict__ out, int n_graphs) {
    int i = blockIdx.x * blockDim.x + threadIdx.x;
    if (i >= n_graphs) return;
    float inv = 1.0f / fmaxf(gcnt[i], 1.0f);
    float z = bo[0];
#pragma unroll
    for (int j = 0; j < 4; ++j) z = fmaf(gsum[i * 4 + j] * inv, Wo[j], z);
    out[i] = 1.0f / (1.0f + expf(-z));
}

extern "C" void kernel_launch(void* const* d_in, const int* in_sizes, int n_in,
                              void* d_out, int out_size, void* d_ws, size_t ws_size,
                              hipStream_t stream) {
    const float* feat = (const float*)d_in[0];
    const int*   src  = (const int*)d_in[1];
    const int*   dst  = (const int*)d_in[2];
    const int*   gid  = (const int*)d_in[3];
    const float* W1   = (const float*)d_in[4];
    const float* b1   = (const float*)d_in[5];
    const float* W2   = (const float*)d_in[6];
    const float* b2   = (const float*)d_in[7];
    const float* Wo   = (const float*)d_in[8];
    const float* bo   = (const float*)d_in[9];
    float* out = (float*)d_out;

    const int n_nodes  = in_sizes[0] / 10;
    const int n_edges  = in_sizes[1];
    const int n_graphs = out_size;
    const int nbk_used = (n_nodes + (1 << BSHIFT) - 1) >> BSHIFT;

    unsigned int* ws32 = (unsigned int*)d_ws;
    const size_t PDW = (size_t)NBKT * CAP;
    const size_t n = (size_t)n_nodes;
    unsigned int*   pd     = ws32;
    unsigned int*   cd     = ws32 + PDW;                   // zeroed
    float*          gsum   = (float*)(cd + NBKT);          // zeroed
    float*          gcnt   = gsum + 4 * (size_t)n_graphs;  // zeroed
    unsigned int*   deg    = (unsigned int*)(gcnt + n_graphs); // [n] zeroed
    float*          onorm  = (float*)(deg + n);            // [n]
    unsigned int*   starts = (unsigned int*)(onorm + n);   // [NBKT*NBIN]
    unsigned int*   y1     = starts + (size_t)NBKT * NBIN; // [2n] dw, 8B aligned
    unsigned int*   y2     = y1 + 2 * n;                   // [n] dw
    u32x4*          part4  = (u32x4*)(y2 + n);             // [n] x 16B
    u32x2*          part2  = (u32x2*)part4;                // aliases part4 (time-muxed)

    (void)hipMemsetAsync(cd, 0,
                         (NBKT + 5 * (size_t)n_graphs + n) * sizeof(unsigned int),
                         stream);

    const int nchunk2 = (n_edges + CHUNK2 - 1) / CHUNK2;
    const int B = 256;

    k_part_dst<<<nchunk2, PTH2, 0, stream>>>(src, dst, pd, cd, deg, n_edges);
    k_sort_dst<<<nbk_used, 512, 0, stream>>>(pd, cd, starts);
    k_node1<<<(n_nodes + B - 1) / B, B, 0, stream>>>(feat, W1, deg, onorm, (uint2*)y1,
                                                     n_nodes);
    k_agg1a<<<nbk_used, 1024, 0, stream>>>(pd, starts, (const uint2*)y1, part4, n_nodes);
    k_agg1b<<<nbk_used, 1024, 0, stream>>>(pd, cd, starts, (const uint2*)y1, part4, b1,
                                           W2, onorm, y2, n_nodes);
    k_agg2a<<<nbk_used, 1024, 0, stream>>>(pd, starts, y2, part2, n_nodes);
    k_agg2b<<<nbk_used, 1024, 0, stream>>>(pd, cd, starts, y2, part2, b2, gid, gsum,
                                           gcnt, n_nodes);
    k_final<<<(n_graphs + B - 1) / B, B, 0, stream>>>(gsum, gcnt, Wo, bo, out, n_graphs);
}

// Round 4
// 681.164 us; speedup vs baseline: 1.6830x; 1.6830x over previous
//
#include <hip/hip_runtime.h>
#include <hip/hip_fp16.h>
#include <math.h>

// ---------------------------------------------------------------------------
// R10: staged partition kept (R9's write-out coalescing worked: pd writes
// ~64 MB), but (a) deg global atomics removed -- they were 512 MB of EA
// traffic + latency wall (device atomics execute memory-side on MI355X), and
// (b) binary-search write-out replaced with per-bucket wave copy (no LDS
// dependent chains). Degree restored via R8b's src partition + histogram,
// now also LDS-staged.
//
// ws layout (dwords):
//   pd     [NBKT*CAP]   (aliased as ps ushort during src phase)
//   cs     [NBKT]  cd [NBKT]  gsum [4G]  gcnt [G]   (zeroed via memset)
//   onorm  [n]
//   starts [NBKT*2048]
//   y1     [2n]   fp8x8 per node (8 B)
//   y2     [n]    fp8x4 per node (4 B)
//   part   [4n]   fp16x8 per node (16 B), reused as fp16x4 (8 B) for agg2
// ---------------------------------------------------------------------------

#define BSHIFT 10
#define BMASK  1023u
#define NBKT   1024
#define CAP    17408u
#define SRT    ((CAP + 511) / 512)
#define NBIN   2048

#define PTH2   1024
#define EPT2   16
#define CHUNK2 (PTH2 * EPT2)   // 16384 edges / block

typedef float v2f __attribute__((ext_vector_type(2)));
typedef unsigned int u32x4 __attribute__((ext_vector_type(4)));
typedef unsigned int u32x2 __attribute__((ext_vector_type(2)));

template <bool HI>
__device__ inline v2f up8(unsigned int w) {
    return __builtin_amdgcn_cvt_pk_f32_fp8((int)w, HI);
}
__device__ inline unsigned int pk4(float a, float b, float c, float d) {
    int r = __builtin_amdgcn_cvt_pk_fp8_f32(a, b, 0, false);
    r = __builtin_amdgcn_cvt_pk_fp8_f32(c, d, r, true);
    return (unsigned int)r;
}
__device__ inline unsigned int pkh(float a, float b) {
    __half2 h = __floats2half2_rn(a, b);
    union { __half2 h; unsigned int u; } c; c.h = h; return c.u;
}
__device__ inline v2f uph(unsigned int u) {
    union { unsigned int u; __half2 h; } c; c.u = u;
    float2 f = __half22float2(c.h);
    v2f r; r.x = f.x; r.y = f.y; return r;
}
__device__ inline void acc8(float* acc, uint2 v) {
    v2f f0 = up8<false>(v.x);
    v2f f1 = up8<true>(v.x);
    v2f f2 = up8<false>(v.y);
    v2f f3 = up8<true>(v.y);
    acc[0] += f0.x; acc[1] += f0.y; acc[2] += f1.x; acc[3] += f1.y;
    acc[4] += f2.x; acc[5] += f2.y; acc[6] += f3.x; acc[7] += f3.y;
}
__device__ inline void acc4(float* acc, unsigned int q) {
    v2f f0 = up8<false>(q);
    v2f f1 = up8<true>(q);
    acc[0] += f0.x; acc[1] += f0.y; acc[2] += f1.x; acc[3] += f1.y;
}

// ---- partition src (keys only, ushort payload), LDS-staged ----------------
__global__ __launch_bounds__(PTH2) void k_part_src(const int* __restrict__ src,
                                                   unsigned short* __restrict__ ps,
                                                   unsigned int* __restrict__ cur,
                                                   int n_edges) {
    __shared__ unsigned int hist[NBKT];
    __shared__ unsigned int scanA[NBKT];
    __shared__ unsigned int scanB[NBKT];
    __shared__ unsigned int gbase[NBKT];
    __shared__ unsigned short stage[CHUNK2];
    const int tid = threadIdx.x;
    const int e0 = blockIdx.x * CHUNK2;
    hist[tid] = 0;                        // PTH2 == NBKT
    __syncthreads();
    unsigned int sv[EPT2];
    unsigned int rk[EPT2];
#pragma unroll
    for (int k = 0; k < EPT2; ++k) {
        int e = e0 + k * PTH2 + tid;
        sv[k] = 0xFFFFFFFFu;
        if (e < n_edges) {
            unsigned int s = (unsigned int)src[e];
            sv[k] = s;
            rk[k] = atomicAdd(&hist[s >> BSHIFT], 1u);
        }
    }
    __syncthreads();
    const unsigned int cnt = hist[tid];
    scanA[tid] = cnt;
    __syncthreads();
    unsigned int* pin = scanA;
    unsigned int* pout = scanB;
    for (int off = 1; off < NBKT; off <<= 1) {
        unsigned int v = pin[tid];
        if (tid >= off) v += pin[tid - off];
        pout[tid] = v;
        __syncthreads();
        unsigned int* t = pin; pin = pout; pout = t;
    }
    gbase[tid] = atomicAdd(&cur[tid], cnt);
    __syncthreads();
#pragma unroll
    for (int k = 0; k < EPT2; ++k) {
        if (sv[k] != 0xFFFFFFFFu) {
            unsigned int b = sv[k] >> BSHIFT;
            unsigned int start = (b == 0) ? 0u : pin[b - 1];
            stage[start + rk[k]] = (unsigned short)(sv[k] & BMASK);
        }
    }
    __syncthreads();
    const int wid = tid >> 6, lane = tid & 63;
    for (int b = wid; b < NBKT; b += (PTH2 >> 6)) {
        unsigned int start = (b == 0) ? 0u : pin[b - 1];
        unsigned int cb = pin[b] - start;
        unsigned int gb = gbase[b];
        for (unsigned int o = lane; o < cb; o += 64)
            ps[(size_t)b * CAP + gb + o] = stage[start + o];
    }
}

// ---- out-degree histogram per src bucket -> onorm -------------------------
__global__ __launch_bounds__(512) void k_deg_src(const unsigned short* __restrict__ ps,
                                                 const unsigned int* __restrict__ cur,
                                                 float* __restrict__ onorm, int n_nodes) {
    __shared__ unsigned int cnt[1 << BSHIFT];
    const int b = blockIdx.x, tid = threadIdx.x;
    for (int i = tid; i < (1 << BSHIFT); i += 512) cnt[i] = 0;
    __syncthreads();
    const unsigned int n = cur[b];
    const unsigned int base = (unsigned int)b * CAP;
    const unsigned int nfull = n & ~4095u;
    for (unsigned int i0 = 0; i0 < nfull; i0 += 4096) {
        uint4 p = *(const uint4*)(ps + base + i0 + (unsigned int)tid * 8u);
        unsigned int w[4] = {p.x, p.y, p.z, p.w};
#pragma unroll
        for (int k = 0; k < 4; ++k) {
            atomicAdd(&cnt[w[k] & 0xFFFFu], 1u);
            atomicAdd(&cnt[w[k] >> 16], 1u);
        }
    }
    for (unsigned int i = nfull + tid; i < n; i += 512) atomicAdd(&cnt[ps[base + i]], 1u);
    __syncthreads();
    for (int r = tid; r < (1 << BSHIFT); r += 512) {
        int node = (b << BSHIFT) + r;
        if (node < n_nodes) onorm[node] = rsqrtf(fmaxf((float)cnt[r], 1.0f));
    }
}

// ---- partition dst (LDS-staged, per-bucket wave write-out) ----------------
__global__ __launch_bounds__(PTH2) void k_part_dst(const int* __restrict__ src,
                                                   const int* __restrict__ dst,
                                                   unsigned int* __restrict__ pd,
                                                   unsigned int* __restrict__ cur,
                                                   int n_edges) {
    __shared__ unsigned int hist[NBKT];
    __shared__ unsigned int scanA[NBKT];
    __shared__ unsigned int scanB[NBKT];
    __shared__ unsigned int gbase[NBKT];
    __shared__ unsigned int stage[CHUNK2];
    const int tid = threadIdx.x;
    const int e0 = blockIdx.x * CHUNK2;
    hist[tid] = 0;                        // PTH2 == NBKT
    __syncthreads();
    unsigned int wv[EPT2];
    unsigned int bb[EPT2];
    unsigned int rk[EPT2];
#pragma unroll
    for (int k = 0; k < EPT2; ++k) {
        int e = e0 + k * PTH2 + tid;
        bb[k] = 0xFFFFFFFFu;
        if (e < n_edges) {
            unsigned int d = (unsigned int)dst[e];
            unsigned int s = (unsigned int)src[e];
            unsigned int b = d >> BSHIFT;
            wv[k] = (s << BSHIFT) | (d & BMASK);
            bb[k] = b;
            rk[k] = atomicAdd(&hist[b], 1u);
        }
    }
    __syncthreads();
    const unsigned int cnt = hist[tid];
    scanA[tid] = cnt;
    __syncthreads();
    unsigned int* pin = scanA;
    unsigned int* pout = scanB;
    for (int off = 1; off < NBKT; off <<= 1) {
        unsigned int v = pin[tid];
        if (tid >= off) v += pin[tid - off];
        pout[tid] = v;
        __syncthreads();
        unsigned int* t = pin; pin = pout; pout = t;
    }
    gbase[tid] = atomicAdd(&cur[tid], cnt);
    __syncthreads();
#pragma unroll
    for (int k = 0; k < EPT2; ++k) {
        if (bb[k] != 0xFFFFFFFFu) {
            unsigned int start = (bb[k] == 0) ? 0u : pin[bb[k] - 1];
            stage[start + rk[k]] = wv[k];
        }
    }
    __syncthreads();
    const int wid = tid >> 6, lane = tid & 63;
    for (int b = wid; b < NBKT; b += (PTH2 >> 6)) {
        unsigned int start = (b == 0) ? 0u : pin[b - 1];
        unsigned int cb = pin[b] - start;
        unsigned int gb = gbase[b];
        for (unsigned int o = lane; o < cb; o += 64)
            pd[(size_t)b * CAP + gb + o] = stage[start + o];
    }
}

// ---- counting sort of one bucket's edges by (dst_low, src_tile) -----------
// key = (dlow << 1) | tile, tile = bit19 of src (= bit29 of payload word).
__global__ __launch_bounds__(512) void k_sort_dst(unsigned int* __restrict__ pd,
                                                  const unsigned int* __restrict__ cur,
                                                  unsigned int* __restrict__ starts) {
    __shared__ unsigned int sA[NBIN];
    __shared__ unsigned int sB[NBIN];
    __shared__ unsigned int curs[NBIN];
    const int b = blockIdx.x, tid = threadIdx.x;
    for (int i = tid; i < NBIN; i += 512) sA[i] = 0;
    __syncthreads();
    const unsigned int n = cur[b];
    const unsigned int base = (unsigned int)b * CAP;
    unsigned int rv[SRT];
#pragma unroll
    for (int k = 0; k < SRT; ++k) {
        unsigned int i = (unsigned int)k * 512u + (unsigned int)tid;
        rv[k] = 0xFFFFFFFFu;
        if (i < n) {
            rv[k] = pd[base + i];
            unsigned int key = ((rv[k] & BMASK) << 1) | ((rv[k] >> 29) & 1u);
            atomicAdd(&sA[key], 1u);
        }
    }
    __syncthreads();
    unsigned int* pin = sA;
    unsigned int* pout = sB;
    for (int off = 1; off < NBIN; off <<= 1) {
        for (int r = tid; r < NBIN; r += 512) {
            unsigned int v = pin[r];
            if (r >= off) v += pin[r - off];
            pout[r] = v;
        }
        __syncthreads();
        unsigned int* t = pin; pin = pout; pout = t;
    }
    for (int r = tid; r < NBIN; r += 512) {
        unsigned int st = (r == 0) ? 0u : pin[r - 1];
        curs[r] = st;
        starts[(size_t)b * NBIN + r] = st;
    }
    __syncthreads();
#pragma unroll
    for (int k = 0; k < SRT; ++k) {
        if (rv[k] != 0xFFFFFFFFu) {
            unsigned int key = ((rv[k] & BMASK) << 1) | ((rv[k] >> 29) & 1u);
            unsigned int pos = atomicAdd(&curs[key], 1u);
            pd[base + pos] = rv[k];
        }
    }
}

// ---- y1 = fp8( (feat @ W1) * onorm )  (10 -> 8) ---------------------------
__global__ void k_node1(const float* __restrict__ feat, const float* __restrict__ W1,
                        const float* __restrict__ onorm, uint2* __restrict__ y1,
                        int n_nodes) {
    int i = blockIdx.x * blockDim.x + threadIdx.x;
    if (i >= n_nodes) return;
    float on = onorm[i];
    const float* fr = feat + (size_t)i * 10;
    float f[10];
#pragma unroll
    for (int k = 0; k < 10; ++k) f[k] = fr[k];
    float acc[8];
#pragma unroll
    for (int j = 0; j < 8; ++j) acc[j] = 0.0f;
#pragma unroll
    for (int k = 0; k < 10; ++k)
#pragma unroll
        for (int j = 0; j < 8; ++j) acc[j] = fmaf(f[k], W1[k * 8 + j], acc[j]);
    uint2 o;
    o.x = pk4(acc[0] * on, acc[1] * on, acc[2] * on, acc[3] * on);
    o.y = pk4(acc[4] * on, acc[5] * on, acc[6] * on, acc[7] * on);
    y1[i] = o;
}

// ---- layer1 agg, tile0: y1[0 .. 2^19) gathers only -> fp16 partial --------
__global__ __launch_bounds__(1024) void k_agg1a(const unsigned int* __restrict__ pd,
                                                const unsigned int* __restrict__ starts,
                                                const uint2* __restrict__ y,
                                                u32x4* __restrict__ part, int n_nodes) {
    const int b = blockIdx.x;
    const int r = threadIdx.x;
    const int node = (b << BSHIFT) + r;
    if (node >= n_nodes) return;
    const unsigned int base = (unsigned int)b * CAP;
    const unsigned int* st = starts + ((size_t)b << 11);
    unsigned int s = st[2 * r];
    unsigned int e = st[2 * r + 1];
    float acc[8];
#pragma unroll
    for (int j = 0; j < 8; ++j) acc[j] = 0.0f;
    unsigned int i = s;
    for (; i + 4 <= e; i += 4) {
        unsigned int w0 = pd[base + i + 0];
        unsigned int w1 = pd[base + i + 1];
        unsigned int w2 = pd[base + i + 2];
        unsigned int w3 = pd[base + i + 3];
        uint2 v0 = y[w0 >> BSHIFT];
        uint2 v1 = y[w1 >> BSHIFT];
        uint2 v2 = y[w2 >> BSHIFT];
        uint2 v3 = y[w3 >> BSHIFT];
        acc8(acc, v0); acc8(acc, v1); acc8(acc, v2); acc8(acc, v3);
    }
    for (; i < e; ++i) acc8(acc, y[pd[base + i] >> BSHIFT]);
    u32x4 p;
    p.x = pkh(acc[0], acc[1]);
    p.y = pkh(acc[2], acc[3]);
    p.z = pkh(acc[4], acc[5]);
    p.w = pkh(acc[6], acc[7]);
    __builtin_nontemporal_store(p, part + node);
}

// ---- layer1 agg, tile1 + partial add + fused node2 ------------------------
__global__ __launch_bounds__(1024) void k_agg1b(const unsigned int* __restrict__ pd,
                                                const unsigned int* __restrict__ cur,
                                                const unsigned int* __restrict__ starts,
                                                const uint2* __restrict__ y,
                                                const u32x4* __restrict__ part,
                                                const float* __restrict__ b1,
                                                const float* __restrict__ W2,
                                                const float* __restrict__ onorm,
                                                unsigned int* __restrict__ y2, int n_nodes) {
    const int b = blockIdx.x;
    const int r = threadIdx.x;
    const int node = (b << BSHIFT) + r;
    if (node >= n_nodes) return;
    const unsigned int base = (unsigned int)b * CAP;
    const unsigned int* st = starts + ((size_t)b << 11);
    unsigned int s0 = st[2 * r];
    unsigned int s = st[2 * r + 1];
    unsigned int e = (r == 1023) ? cur[b] : st[2 * r + 2];
    float acc[8];
#pragma unroll
    for (int j = 0; j < 8; ++j) acc[j] = 0.0f;
    unsigned int i = s;
    for (; i + 4 <= e; i += 4) {
        unsigned int w0 = pd[base + i + 0];
        unsigned int w1 = pd[base + i + 1];
        unsigned int w2 = pd[base + i + 2];
        unsigned int w3 = pd[base + i + 3];
        uint2 v0 = y[w0 >> BSHIFT];
        uint2 v1 = y[w1 >> BSHIFT];
        uint2 v2 = y[w2 >> BSHIFT];
        uint2 v3 = y[w3 >> BSHIFT];
        acc8(acc, v0); acc8(acc, v1); acc8(acc, v2); acc8(acc, v3);
    }
    for (; i < e; ++i) acc8(acc, y[pd[base + i] >> BSHIFT]);
    u32x4 p = __builtin_nontemporal_load(part + node);
    v2f q0 = uph(p.x), q1 = uph(p.y), q2 = uph(p.z), q3 = uph(p.w);
    acc[0] += q0.x; acc[1] += q0.y; acc[2] += q1.x; acc[3] += q1.y;
    acc[4] += q2.x; acc[5] += q2.y; acc[6] += q3.x; acc[7] += q3.y;
    float inn = rsqrtf(fmaxf((float)(e - s0), 1.0f));
    float h[8];
#pragma unroll
    for (int j = 0; j < 8; ++j) h[j] = fmaxf(fmaf(acc[j], inn, b1[j]), 0.0f);
    float z[4] = {0.0f, 0.0f, 0.0f, 0.0f};
#pragma unroll
    for (int k = 0; k < 8; ++k)
#pragma unroll
        for (int j = 0; j < 4; ++j) z[j] = fmaf(h[k], W2[k * 4 + j], z[j]);
    float on = onorm[node];
    y2[node] = pk4(z[0] * on, z[1] * on, z[2] * on, z[3] * on);
}

// ---- layer2 agg, tile0 -> fp16 partial ------------------------------------
__global__ __launch_bounds__(1024) void k_agg2a(const unsigned int* __restrict__ pd,
                                                const unsigned int* __restrict__ starts,
                                                const unsigned int* __restrict__ y,
                                                u32x2* __restrict__ part, int n_nodes) {
    const int b = blockIdx.x;
    const int r = threadIdx.x;
    const int node = (b << BSHIFT) + r;
    if (node >= n_nodes) return;
    const unsigned int base = (unsigned int)b * CAP;
    const unsigned int* st = starts + ((size_t)b << 11);
    unsigned int s = st[2 * r];
    unsigned int e = st[2 * r + 1];
    float acc[4] = {0.0f, 0.0f, 0.0f, 0.0f};
    unsigned int i = s;
    for (; i + 4 <= e; i += 4) {
        unsigned int w0 = pd[base + i + 0];
        unsigned int w1 = pd[base + i + 1];
        unsigned int w2 = pd[base + i + 2];
        unsigned int w3 = pd[base + i + 3];
        unsigned int q0 = y[w0 >> BSHIFT];
        unsigned int q1 = y[w1 >> BSHIFT];
        unsigned int q2 = y[w2 >> BSHIFT];
        unsigned int q3 = y[w3 >> BSHIFT];
        acc4(acc, q0); acc4(acc, q1); acc4(acc, q2); acc4(acc, q3);
    }
    for (; i < e; ++i) acc4(acc, y[pd[base + i] >> BSHIFT]);
    u32x2 p;
    p.x = pkh(acc[0], acc[1]);
    p.y = pkh(acc[2], acc[3]);
    __builtin_nontemporal_store(p, part + node);
}

// ---- layer2 agg, tile1 + partial add + fused graph pooling ----------------
__global__ __launch_bounds__(1024) void k_agg2b(const unsigned int* __restrict__ pd,
                                                const unsigned int* __restrict__ cur,
                                                const unsigned int* __restrict__ starts,
                                                const unsigned int* __restrict__ y,
                                                const u32x2* __restrict__ part,
                                                const float* __restrict__ b2,
                                                const int* __restrict__ gid,
                                                float* __restrict__ gsum,
                                                float* __restrict__ gcnt, int n_nodes) {
    const int b = blockIdx.x;
    const int r = threadIdx.x;
    const int node = (b << BSHIFT) + r;
    const int lane = threadIdx.x & 63;
    int g = -1;
    float v0 = 0.f, v1 = 0.f, v2 = 0.f, v3 = 0.f, c = 0.f;
    if (node < n_nodes) {
        const unsigned int base = (unsigned int)b * CAP;
        const unsigned int* st = starts + ((size_t)b << 11);
        unsigned int s0 = st[2 * r];
        unsigned int s = st[2 * r + 1];
        unsigned int e = (r == 1023) ? cur[b] : st[2 * r + 2];
        float acc[4] = {0.0f, 0.0f, 0.0f, 0.0f};
        unsigned int i = s;
        for (; i + 4 <= e; i += 4) {
            unsigned int w0 = pd[base + i + 0];
            unsigned int w1 = pd[base + i + 1];
            unsigned int w2 = pd[base + i + 2];
            unsigned int w3 = pd[base + i + 3];
            unsigned int q0 = y[w0 >> BSHIFT];
            unsigned int q1 = y[w1 >> BSHIFT];
            unsigned int q2 = y[w2 >> BSHIFT];
            unsigned int q3 = y[w3 >> BSHIFT];
            acc4(acc, q0); acc4(acc, q1); acc4(acc, q2); acc4(acc, q3);
        }
        for (; i < e; ++i) acc4(acc, y[pd[base + i] >> BSHIFT]);
        u32x2 p = __builtin_nontemporal_load(part + node);
        v2f p0 = uph(p.x), p1 = uph(p.y);
        acc[0] += p0.x; acc[1] += p0.y; acc[2] += p1.x; acc[3] += p1.y;
        float inn = rsqrtf(fmaxf((float)(e - s0), 1.0f));
        v0 = fmaxf(fmaf(acc[0], inn, b2[0]), 0.0f);
        v1 = fmaxf(fmaf(acc[1], inn, b2[1]), 0.0f);
        v2 = fmaxf(fmaf(acc[2], inn, b2[2]), 0.0f);
        v3 = fmaxf(fmaf(acc[3], inn, b2[3]), 0.0f);
        c = 1.0f;
        g = gid[node];
    }
#pragma unroll
    for (int sft = 1; sft < 64; sft <<= 1) {
        int go   = __shfl_down(g, sft);
        float t0 = __shfl_down(v0, sft);
        float t1 = __shfl_down(v1, sft);
        float t2 = __shfl_down(v2, sft);
        float t3 = __shfl_down(v3, sft);
        float tc = __shfl_down(c, sft);
        if (lane + sft < 64 && go == g) {
            v0 += t0; v1 += t1; v2 += t2; v3 += t3; c += tc;
        }
    }
    int gp = __shfl_up(g, 1);
    bool head = (lane == 0) || (gp != g);
    if (g >= 0 && head) {
        unsafeAtomicAdd(&gsum[g * 4 + 0], v0);
        unsafeAtomicAdd(&gsum[g * 4 + 1], v1);
        unsafeAtomicAdd(&gsum[g * 4 + 2], v2);
        unsafeAtomicAdd(&gsum[g * 4 + 3], v3);
        unsafeAtomicAdd(&gcnt[g], c);
    }
}

__global__ void k_final(const float* __restrict__ gsum, const float* __restrict__ gcnt,
                        const float* __restrict__ Wo, const float* __restrict__ bo,
                        float* __restrict__ out, int n_graphs) {
    int i = blockIdx.x * blockDim.x + threadIdx.x;
    if (i >= n_graphs) return;
    float inv = 1.0f / fmaxf(gcnt[i], 1.0f);
    float z = bo[0];
#pragma unroll
    for (int j = 0; j < 4; ++j) z = fmaf(gsum[i * 4 + j] * inv, Wo[j], z);
    out[i] = 1.0f / (1.0f + expf(-z));
}

extern "C" void kernel_launch(void* const* d_in, const int* in_sizes, int n_in,
                              void* d_out, int out_size, void* d_ws, size_t ws_size,
                              hipStream_t stream) {
    const float* feat = (const float*)d_in[0];
    const int*   src  = (const int*)d_in[1];
    const int*   dst  = (const int*)d_in[2];
    const int*   gid  = (const int*)d_in[3];
    const float* W1   = (const float*)d_in[4];
    const float* b1   = (const float*)d_in[5];
    const float* W2   = (const float*)d_in[6];
    const float* b2   = (const float*)d_in[7];
    const float* Wo   = (const float*)d_in[8];
    const float* bo   = (const float*)d_in[9];
    float* out = (float*)d_out;

    const int n_nodes  = in_sizes[0] / 10;
    const int n_edges  = in_sizes[1];
    const int n_graphs = out_size;
    const int nbk_used = (n_nodes + (1 << BSHIFT) - 1) >> BSHIFT;

    unsigned int* ws32 = (unsigned int*)d_ws;
    const size_t PDW = (size_t)NBKT * CAP;
    const size_t n = (size_t)n_nodes;
    unsigned int*   pd     = ws32;
    unsigned short* ps     = (unsigned short*)ws32;        // aliases pd (time-muxed)
    unsigned int*   cs     = ws32 + PDW;                   // zeroed
    unsigned int*   cd     = cs + NBKT;                    // zeroed
    float*          gsum   = (float*)(cd + NBKT);          // zeroed
    float*          gcnt   = gsum + 4 * (size_t)n_graphs;  // zeroed
    float*          onorm  = gcnt + n_graphs;              // [n]
    unsigned int*   starts = (unsigned int*)(onorm + n);   // [NBKT*NBIN]
    unsigned int*   y1     = starts + (size_t)NBKT * NBIN; // [2n] dw, 8B aligned
    unsigned int*   y2     = y1 + 2 * n;                   // [n] dw
    u32x4*          part4  = (u32x4*)(y2 + n);             // [n] x 16B
    u32x2*          part2  = (u32x2*)part4;                // aliases part4 (time-muxed)

    (void)hipMemsetAsync(cs, 0, (2 * NBKT + 5 * (size_t)n_graphs) * sizeof(unsigned int),
                         stream);

    const int nchunk2 = (n_edges + CHUNK2 - 1) / CHUNK2;
    const int B = 256;

    k_part_src<<<nchunk2, PTH2, 0, stream>>>(src, ps, cs, n_edges);
    k_deg_src<<<nbk_used, 512, 0, stream>>>(ps, cs, onorm, n_nodes);
    k_part_dst<<<nchunk2, PTH2, 0, stream>>>(src, dst, pd, cd, n_edges);
    k_sort_dst<<<nbk_used, 512, 0, stream>>>(pd, cd, starts);
    k_node1<<<(n_nodes + B - 1) / B, B, 0, stream>>>(feat, W1, onorm, (uint2*)y1, n_nodes);
    k_agg1a<<<nbk_used, 1024, 0, stream>>>(pd, starts, (const uint2*)y1, part4, n_nodes);
    k_agg1b<<<nbk_used, 1024, 0, stream>>>(pd, cd, starts, (const uint2*)y1, part4, b1,
                                           W2, onorm, y2, n_nodes);
    k_agg2a<<<nbk_used, 1024, 0, stream>>>(pd, starts, y2, part2, n_nodes);
    k_agg2b<<<nbk_used, 1024, 0, stream>>>(pd, cd, starts, y2, part2, b2, gid, gsum,
                                           gcnt, n_nodes);
    k_final<<<(n_graphs + B - 1) / B, B, 0, stream>>>(gsum, gcnt, Wo, bo, out, n_graphs);
}

// Round 5
// 640.433 us; speedup vs baseline: 1.7901x; 1.0636x over previous
//
#include <hip/hip_runtime.h>
#include <hip/hip_fp16.h>
#include <math.h>

// ---------------------------------------------------------------------------
// R11: LDS-staged write-out for k_sort_dst.
// R10 counters: k_sort_dst = 91.6 us, WRITE 201 MB for a 64 MB sorted payload
// (3x): the random 4B in-bucket scatter dirties 64B lines that get evicted
// partially-written (resident bucket set ~4.4 MB/XCD > 4 MB L2). Fix: compute
// final positions in registers, scatter into a half-bucket LDS stage (2
// passes), copy stage->pd linearly. Random stores now hit LDS, global stores
// are write-once full lines. Everything else unchanged from R10.
//
// ws layout (dwords):
//   pd     [NBKT*CAP]   (aliased as ps ushort during src phase)
//   cs     [NBKT]  cd [NBKT]  gsum [4G]  gcnt [G]   (zeroed via memset)
//   onorm  [n]
//   starts [NBKT*2048]
//   y1     [2n]   fp8x8 per node (8 B)
//   y2     [n]    fp8x4 per node (4 B)
//   part   [4n]   fp16x8 per node (16 B), reused as fp16x4 (8 B) for agg2
// ---------------------------------------------------------------------------

#define BSHIFT 10
#define BMASK  1023u
#define NBKT   1024
#define CAP    17408u
#define SRT    ((CAP + 511) / 512)
#define NBIN   2048
#define HSTAGE (CAP / 2)       // 8704 dwords = 34816 B LDS stage

#define PTH2   1024
#define EPT2   16
#define CHUNK2 (PTH2 * EPT2)   // 16384 edges / block

typedef float v2f __attribute__((ext_vector_type(2)));
typedef unsigned int u32x4 __attribute__((ext_vector_type(4)));
typedef unsigned int u32x2 __attribute__((ext_vector_type(2)));

template <bool HI>
__device__ inline v2f up8(unsigned int w) {
    return __builtin_amdgcn_cvt_pk_f32_fp8((int)w, HI);
}
__device__ inline unsigned int pk4(float a, float b, float c, float d) {
    int r = __builtin_amdgcn_cvt_pk_fp8_f32(a, b, 0, false);
    r = __builtin_amdgcn_cvt_pk_fp8_f32(c, d, r, true);
    return (unsigned int)r;
}
__device__ inline unsigned int pkh(float a, float b) {
    __half2 h = __floats2half2_rn(a, b);
    union { __half2 h; unsigned int u; } c; c.h = h; return c.u;
}
__device__ inline v2f uph(unsigned int u) {
    union { unsigned int u; __half2 h; } c; c.u = u;
    float2 f = __half22float2(c.h);
    v2f r; r.x = f.x; r.y = f.y; return r;
}
__device__ inline void acc8(float* acc, uint2 v) {
    v2f f0 = up8<false>(v.x);
    v2f f1 = up8<true>(v.x);
    v2f f2 = up8<false>(v.y);
    v2f f3 = up8<true>(v.y);
    acc[0] += f0.x; acc[1] += f0.y; acc[2] += f1.x; acc[3] += f1.y;
    acc[4] += f2.x; acc[5] += f2.y; acc[6] += f3.x; acc[7] += f3.y;
}
__device__ inline void acc4(float* acc, unsigned int q) {
    v2f f0 = up8<false>(q);
    v2f f1 = up8<true>(q);
    acc[0] += f0.x; acc[1] += f0.y; acc[2] += f1.x; acc[3] += f1.y;
}

// ---- partition src (keys only, ushort payload), LDS-staged ----------------
__global__ __launch_bounds__(PTH2) void k_part_src(const int* __restrict__ src,
                                                   unsigned short* __restrict__ ps,
                                                   unsigned int* __restrict__ cur,
                                                   int n_edges) {
    __shared__ unsigned int hist[NBKT];
    __shared__ unsigned int scanA[NBKT];
    __shared__ unsigned int scanB[NBKT];
    __shared__ unsigned int gbase[NBKT];
    __shared__ unsigned short stage[CHUNK2];
    const int tid = threadIdx.x;
    const int e0 = blockIdx.x * CHUNK2;
    hist[tid] = 0;                        // PTH2 == NBKT
    __syncthreads();
    unsigned int sv[EPT2];
    unsigned int rk[EPT2];
#pragma unroll
    for (int k = 0; k < EPT2; ++k) {
        int e = e0 + k * PTH2 + tid;
        sv[k] = 0xFFFFFFFFu;
        if (e < n_edges) {
            unsigned int s = (unsigned int)src[e];
            sv[k] = s;
            rk[k] = atomicAdd(&hist[s >> BSHIFT], 1u);
        }
    }
    __syncthreads();
    const unsigned int cnt = hist[tid];
    scanA[tid] = cnt;
    __syncthreads();
    unsigned int* pin = scanA;
    unsigned int* pout = scanB;
    for (int off = 1; off < NBKT; off <<= 1) {
        unsigned int v = pin[tid];
        if (tid >= off) v += pin[tid - off];
        pout[tid] = v;
        __syncthreads();
        unsigned int* t = pin; pin = pout; pout = t;
    }
    gbase[tid] = atomicAdd(&cur[tid], cnt);
    __syncthreads();
#pragma unroll
    for (int k = 0; k < EPT2; ++k) {
        if (sv[k] != 0xFFFFFFFFu) {
            unsigned int b = sv[k] >> BSHIFT;
            unsigned int start = (b == 0) ? 0u : pin[b - 1];
            stage[start + rk[k]] = (unsigned short)(sv[k] & BMASK);
        }
    }
    __syncthreads();
    const int wid = tid >> 6, lane = tid & 63;
    for (int b = wid; b < NBKT; b += (PTH2 >> 6)) {
        unsigned int start = (b == 0) ? 0u : pin[b - 1];
        unsigned int cb = pin[b] - start;
        unsigned int gb = gbase[b];
        for (unsigned int o = lane; o < cb; o += 64)
            ps[(size_t)b * CAP + gb + o] = stage[start + o];
    }
}

// ---- out-degree histogram per src bucket -> onorm -------------------------
__global__ __launch_bounds__(512) void k_deg_src(const unsigned short* __restrict__ ps,
                                                 const unsigned int* __restrict__ cur,
                                                 float* __restrict__ onorm, int n_nodes) {
    __shared__ unsigned int cnt[1 << BSHIFT];
    const int b = blockIdx.x, tid = threadIdx.x;
    for (int i = tid; i < (1 << BSHIFT); i += 512) cnt[i] = 0;
    __syncthreads();
    const unsigned int n = cur[b];
    const unsigned int base = (unsigned int)b * CAP;
    const unsigned int nfull = n & ~4095u;
    for (unsigned int i0 = 0; i0 < nfull; i0 += 4096) {
        uint4 p = *(const uint4*)(ps + base + i0 + (unsigned int)tid * 8u);
        unsigned int w[4] = {p.x, p.y, p.z, p.w};
#pragma unroll
        for (int k = 0; k < 4; ++k) {
            atomicAdd(&cnt[w[k] & 0xFFFFu], 1u);
            atomicAdd(&cnt[w[k] >> 16], 1u);
        }
    }
    for (unsigned int i = nfull + tid; i < n; i += 512) atomicAdd(&cnt[ps[base + i]], 1u);
    __syncthreads();
    for (int r = tid; r < (1 << BSHIFT); r += 512) {
        int node = (b << BSHIFT) + r;
        if (node < n_nodes) onorm[node] = rsqrtf(fmaxf((float)cnt[r], 1.0f));
    }
}

// ---- partition dst (LDS-staged, per-bucket wave write-out) ----------------
__global__ __launch_bounds__(PTH2) void k_part_dst(const int* __restrict__ src,
                                                   const int* __restrict__ dst,
                                                   unsigned int* __restrict__ pd,
                                                   unsigned int* __restrict__ cur,
                                                   int n_edges) {
    __shared__ unsigned int hist[NBKT];
    __shared__ unsigned int scanA[NBKT];
    __shared__ unsigned int scanB[NBKT];
    __shared__ unsigned int gbase[NBKT];
    __shared__ unsigned int stage[CHUNK2];
    const int tid = threadIdx.x;
    const int e0 = blockIdx.x * CHUNK2;
    hist[tid] = 0;                        // PTH2 == NBKT
    __syncthreads();
    unsigned int wv[EPT2];
    unsigned int bb[EPT2];
    unsigned int rk[EPT2];
#pragma unroll
    for (int k = 0; k < EPT2; ++k) {
        int e = e0 + k * PTH2 + tid;
        bb[k] = 0xFFFFFFFFu;
        if (e < n_edges) {
            unsigned int d = (unsigned int)dst[e];
            unsigned int s = (unsigned int)src[e];
            unsigned int b = d >> BSHIFT;
            wv[k] = (s << BSHIFT) | (d & BMASK);
            bb[k] = b;
            rk[k] = atomicAdd(&hist[b], 1u);
        }
    }
    __syncthreads();
    const unsigned int cnt = hist[tid];
    scanA[tid] = cnt;
    __syncthreads();
    unsigned int* pin = scanA;
    unsigned int* pout = scanB;
    for (int off = 1; off < NBKT; off <<= 1) {
        unsigned int v = pin[tid];
        if (tid >= off) v += pin[tid - off];
        pout[tid] = v;
        __syncthreads();
        unsigned int* t = pin; pin = pout; pout = t;
    }
    gbase[tid] = atomicAdd(&cur[tid], cnt);
    __syncthreads();
#pragma unroll
    for (int k = 0; k < EPT2; ++k) {
        if (bb[k] != 0xFFFFFFFFu) {
            unsigned int start = (bb[k] == 0) ? 0u : pin[bb[k] - 1];
            stage[start + rk[k]] = wv[k];
        }
    }
    __syncthreads();
    const int wid = tid >> 6, lane = tid & 63;
    for (int b = wid; b < NBKT; b += (PTH2 >> 6)) {
        unsigned int start = (b == 0) ? 0u : pin[b - 1];
        unsigned int cb = pin[b] - start;
        unsigned int gb = gbase[b];
        for (unsigned int o = lane; o < cb; o += 64)
            pd[(size_t)b * CAP + gb + o] = stage[start + o];
    }
}

// ---- counting sort by (dst_low, src_tile), LDS-staged write-out -----------
// key = (dlow << 1) | tile, tile = bit19 of src (= bit29 of payload word).
__global__ __launch_bounds__(512) void k_sort_dst(unsigned int* __restrict__ pd,
                                                  const unsigned int* __restrict__ cur,
                                                  unsigned int* __restrict__ starts) {
    __shared__ unsigned int sA[NBIN];
    __shared__ unsigned int sB[NBIN];
    __shared__ unsigned int curs[NBIN];
    __shared__ unsigned int stage[HSTAGE];
    const int b = blockIdx.x, tid = threadIdx.x;
    for (int i = tid; i < NBIN; i += 512) sA[i] = 0;
    __syncthreads();
    const unsigned int n = cur[b];
    const unsigned int base = (unsigned int)b * CAP;
    unsigned int rv[SRT];
#pragma unroll
    for (int k = 0; k < SRT; ++k) {
        unsigned int i = (unsigned int)k * 512u + (unsigned int)tid;
        rv[k] = 0xFFFFFFFFu;
        if (i < n) {
            rv[k] = pd[base + i];
            unsigned int key = ((rv[k] & BMASK) << 1) | ((rv[k] >> 29) & 1u);
            atomicAdd(&sA[key], 1u);
        }
    }
    __syncthreads();
    unsigned int* pin = sA;
    unsigned int* pout = sB;
    for (int off = 1; off < NBIN; off <<= 1) {
        for (int r = tid; r < NBIN; r += 512) {
            unsigned int v = pin[r];
            if (r >= off) v += pin[r - off];
            pout[r] = v;
        }
        __syncthreads();
        unsigned int* t = pin; pin = pout; pout = t;
    }
    for (int r = tid; r < NBIN; r += 512) {
        unsigned int st = (r == 0) ? 0u : pin[r - 1];
        curs[r] = st;
        starts[(size_t)b * NBIN + r] = st;
    }
    __syncthreads();
    // final in-bucket positions, register-resident
    unsigned int pos[SRT];
#pragma unroll
    for (int k = 0; k < SRT; ++k) {
        pos[k] = 0xFFFFFFFFu;
        if (rv[k] != 0xFFFFFFFFu) {
            unsigned int key = ((rv[k] & BMASK) << 1) | ((rv[k] >> 29) & 1u);
            pos[k] = atomicAdd(&curs[key], 1u);
        }
    }
    __syncthreads();
    // pass 0: positions [0, HSTAGE)
#pragma unroll
    for (int k = 0; k < SRT; ++k)
        if (pos[k] < HSTAGE) stage[pos[k]] = rv[k];
    __syncthreads();
    const unsigned int lim0 = (n < HSTAGE) ? n : HSTAGE;
    for (unsigned int i = tid; i < lim0; i += 512) pd[base + i] = stage[i];
    __syncthreads();
    // pass 1: positions [HSTAGE, n)
#pragma unroll
    for (int k = 0; k < SRT; ++k)
        if (pos[k] != 0xFFFFFFFFu && pos[k] >= HSTAGE) stage[pos[k] - HSTAGE] = rv[k];
    __syncthreads();
    for (unsigned int i = HSTAGE + tid; i < n; i += 512) pd[base + i] = stage[i - HSTAGE];
}

// ---- y1 = fp8( (feat @ W1) * onorm )  (10 -> 8) ---------------------------
__global__ void k_node1(const float* __restrict__ feat, const float* __restrict__ W1,
                        const float* __restrict__ onorm, uint2* __restrict__ y1,
                        int n_nodes) {
    int i = blockIdx.x * blockDim.x + threadIdx.x;
    if (i >= n_nodes) return;
    float on = onorm[i];
    const float* fr = feat + (size_t)i * 10;
    float f[10];
#pragma unroll
    for (int k = 0; k < 10; ++k) f[k] = fr[k];
    float acc[8];
#pragma unroll
    for (int j = 0; j < 8; ++j) acc[j] = 0.0f;
#pragma unroll
    for (int k = 0; k < 10; ++k)
#pragma unroll
        for (int j = 0; j < 8; ++j) acc[j] = fmaf(f[k], W1[k * 8 + j], acc[j]);
    uint2 o;
    o.x = pk4(acc[0] * on, acc[1] * on, acc[2] * on, acc[3] * on);
    o.y = pk4(acc[4] * on, acc[5] * on, acc[6] * on, acc[7] * on);
    y1[i] = o;
}

// ---- layer1 agg, tile0: y1[0 .. 2^19) gathers only -> fp16 partial --------
__global__ __launch_bounds__(1024) void k_agg1a(const unsigned int* __restrict__ pd,
                                                const unsigned int* __restrict__ starts,
                                                const uint2* __restrict__ y,
                                                u32x4* __restrict__ part, int n_nodes) {
    const int b = blockIdx.x;
    const int r = threadIdx.x;
    const int node = (b << BSHIFT) + r;
    if (node >= n_nodes) return;
    const unsigned int base = (unsigned int)b * CAP;
    const unsigned int* st = starts + ((size_t)b << 11);
    unsigned int s = st[2 * r];
    unsigned int e = st[2 * r + 1];
    float acc[8];
#pragma unroll
    for (int j = 0; j < 8; ++j) acc[j] = 0.0f;
    unsigned int i = s;
    for (; i + 4 <= e; i += 4) {
        unsigned int w0 = pd[base + i + 0];
        unsigned int w1 = pd[base + i + 1];
        unsigned int w2 = pd[base + i + 2];
        unsigned int w3 = pd[base + i + 3];
        uint2 v0 = y[w0 >> BSHIFT];
        uint2 v1 = y[w1 >> BSHIFT];
        uint2 v2 = y[w2 >> BSHIFT];
        uint2 v3 = y[w3 >> BSHIFT];
        acc8(acc, v0); acc8(acc, v1); acc8(acc, v2); acc8(acc, v3);
    }
    for (; i < e; ++i) acc8(acc, y[pd[base + i] >> BSHIFT]);
    u32x4 p;
    p.x = pkh(acc[0], acc[1]);
    p.y = pkh(acc[2], acc[3]);
    p.z = pkh(acc[4], acc[5]);
    p.w = pkh(acc[6], acc[7]);
    __builtin_nontemporal_store(p, part + node);
}

// ---- layer1 agg, tile1 + partial add + fused node2 ------------------------
__global__ __launch_bounds__(1024) void k_agg1b(const unsigned int* __restrict__ pd,
                                                const unsigned int* __restrict__ cur,
                                                const unsigned int* __restrict__ starts,
                                                const uint2* __restrict__ y,
                                                const u32x4* __restrict__ part,
                                                const float* __restrict__ b1,
                                                const float* __restrict__ W2,
                                                const float* __restrict__ onorm,
                                                unsigned int* __restrict__ y2, int n_nodes) {
    const int b = blockIdx.x;
    const int r = threadIdx.x;
    const int node = (b << BSHIFT) + r;
    if (node >= n_nodes) return;
    const unsigned int base = (unsigned int)b * CAP;
    const unsigned int* st = starts + ((size_t)b << 11);
    unsigned int s0 = st[2 * r];
    unsigned int s = st[2 * r + 1];
    unsigned int e = (r == 1023) ? cur[b] : st[2 * r + 2];
    float acc[8];
#pragma unroll
    for (int j = 0; j < 8; ++j) acc[j] = 0.0f;
    unsigned int i = s;
    for (; i + 4 <= e; i += 4) {
        unsigned int w0 = pd[base + i + 0];
        unsigned int w1 = pd[base + i + 1];
        unsigned int w2 = pd[base + i + 2];
        unsigned int w3 = pd[base + i + 3];
        uint2 v0 = y[w0 >> BSHIFT];
        uint2 v1 = y[w1 >> BSHIFT];
        uint2 v2 = y[w2 >> BSHIFT];
        uint2 v3 = y[w3 >> BSHIFT];
        acc8(acc, v0); acc8(acc, v1); acc8(acc, v2); acc8(acc, v3);
    }
    for (; i < e; ++i) acc8(acc, y[pd[base + i] >> BSHIFT]);
    u32x4 p = __builtin_nontemporal_load(part + node);
    v2f q0 = uph(p.x), q1 = uph(p.y), q2 = uph(p.z), q3 = uph(p.w);
    acc[0] += q0.x; acc[1] += q0.y; acc[2] += q1.x; acc[3] += q1.y;
    acc[4] += q2.x; acc[5] += q2.y; acc[6] += q3.x; acc[7] += q3.y;
    float inn = rsqrtf(fmaxf((float)(e - s0), 1.0f));
    float h[8];
#pragma unroll
    for (int j = 0; j < 8; ++j) h[j] = fmaxf(fmaf(acc[j], inn, b1[j]), 0.0f);
    float z[4] = {0.0f, 0.0f, 0.0f, 0.0f};
#pragma unroll
    for (int k = 0; k < 8; ++k)
#pragma unroll
        for (int j = 0; j < 4; ++j) z[j] = fmaf(h[k], W2[k * 4 + j], z[j]);
    float on = onorm[node];
    y2[node] = pk4(z[0] * on, z[1] * on, z[2] * on, z[3] * on);
}

// ---- layer2 agg, tile0 -> fp16 partial ------------------------------------
__global__ __launch_bounds__(1024) void k_agg2a(const unsigned int* __restrict__ pd,
                                                const unsigned int* __restrict__ starts,
                                                const unsigned int* __restrict__ y,
                                                u32x2* __restrict__ part, int n_nodes) {
    const int b = blockIdx.x;
    const int r = threadIdx.x;
    const int node = (b << BSHIFT) + r;
    if (node >= n_nodes) return;
    const unsigned int base = (unsigned int)b * CAP;
    const unsigned int* st = starts + ((size_t)b << 11);
    unsigned int s = st[2 * r];
    unsigned int e = st[2 * r + 1];
    float acc[4] = {0.0f, 0.0f, 0.0f, 0.0f};
    unsigned int i = s;
    for (; i + 4 <= e; i += 4) {
        unsigned int w0 = pd[base + i + 0];
        unsigned int w1 = pd[base + i + 1];
        unsigned int w2 = pd[base + i + 2];
        unsigned int w3 = pd[base + i + 3];
        unsigned int q0 = y[w0 >> BSHIFT];
        unsigned int q1 = y[w1 >> BSHIFT];
        unsigned int q2 = y[w2 >> BSHIFT];
        unsigned int q3 = y[w3 >> BSHIFT];
        acc4(acc, q0); acc4(acc, q1); acc4(acc, q2); acc4(acc, q3);
    }
    for (; i < e; ++i) acc4(acc, y[pd[base + i] >> BSHIFT]);
    u32x2 p;
    p.x = pkh(acc[0], acc[1]);
    p.y = pkh(acc[2], acc[3]);
    __builtin_nontemporal_store(p, part + node);
}

// ---- layer2 agg, tile1 + partial add + fused graph pooling ----------------
__global__ __launch_bounds__(1024) void k_agg2b(const unsigned int* __restrict__ pd,
                                                const unsigned int* __restrict__ cur,
                                                const unsigned int* __restrict__ starts,
                                                const unsigned int* __restrict__ y,
                                                const u32x2* __restrict__ part,
                                                const float* __restrict__ b2,
                                                const int* __restrict__ gid,
                                                float* __restrict__ gsum,
                                                float* __restrict__ gcnt, int n_nodes) {
    const int b = blockIdx.x;
    const int r = threadIdx.x;
    const int node = (b << BSHIFT) + r;
    const int lane = threadIdx.x & 63;
    int g = -1;
    float v0 = 0.f, v1 = 0.f, v2 = 0.f, v3 = 0.f, c = 0.f;
    if (node < n_nodes) {
        const unsigned int base = (unsigned int)b * CAP;
        const unsigned int* st = starts + ((size_t)b << 11);
        unsigned int s0 = st[2 * r];
        unsigned int s = st[2 * r + 1];
        unsigned int e = (r == 1023) ? cur[b] : st[2 * r + 2];
        float acc[4] = {0.0f, 0.0f, 0.0f, 0.0f};
        unsigned int i = s;
        for (; i + 4 <= e; i += 4) {
            unsigned int w0 = pd[base + i + 0];
            unsigned int w1 = pd[base + i + 1];
            unsigned int w2 = pd[base + i + 2];
            unsigned int w3 = pd[base + i + 3];
            unsigned int q0 = y[w0 >> BSHIFT];
            unsigned int q1 = y[w1 >> BSHIFT];
            unsigned int q2 = y[w2 >> BSHIFT];
            unsigned int q3 = y[w3 >> BSHIFT];
            acc4(acc, q0); acc4(acc, q1); acc4(acc, q2); acc4(acc, q3);
        }
        for (; i < e; ++i) acc4(acc, y[pd[base + i] >> BSHIFT]);
        u32x2 p = __builtin_nontemporal_load(part + node);
        v2f p0 = uph(p.x), p1 = uph(p.y);
        acc[0] += p0.x; acc[1] += p0.y; acc[2] += p1.x; acc[3] += p1.y;
        float inn = rsqrtf(fmaxf((float)(e - s0), 1.0f));
        v0 = fmaxf(fmaf(acc[0], inn, b2[0]), 0.0f);
        v1 = fmaxf(fmaf(acc[1], inn, b2[1]), 0.0f);
        v2 = fmaxf(fmaf(acc[2], inn, b2[2]), 0.0f);
        v3 = fmaxf(fmaf(acc[3], inn, b2[3]), 0.0f);
        c = 1.0f;
        g = gid[node];
    }
#pragma unroll
    for (int sft = 1; sft < 64; sft <<= 1) {
        int go   = __shfl_down(g, sft);
        float t0 = __shfl_down(v0, sft);
        float t1 = __shfl_down(v1, sft);
        float t2 = __shfl_down(v2, sft);
        float t3 = __shfl_down(v3, sft);
        float tc = __shfl_down(c, sft);
        if (lane + sft < 64 && go == g) {
            v0 += t0; v1 += t1; v2 += t2; v3 += t3; c += tc;
        }
    }
    int gp = __shfl_up(g, 1);
    bool head = (lane == 0) || (gp != g);
    if (g >= 0 && head) {
        unsafeAtomicAdd(&gsum[g * 4 + 0], v0);
        unsafeAtomicAdd(&gsum[g * 4 + 1], v1);
        unsafeAtomicAdd(&gsum[g * 4 + 2], v2);
        unsafeAtomicAdd(&gsum[g * 4 + 3], v3);
        unsafeAtomicAdd(&gcnt[g], c);
    }
}

__global__ void k_final(const float* __restrict__ gsum, const float* __restrict__ gcnt,
                        const float* __restrict__ Wo, const float* __restrict__ bo,
                        float* __restrict__ out, int n_graphs) {
    int i = blockIdx.x * blockDim.x + threadIdx.x;
    if (i >= n_graphs) return;
    float inv = 1.0f / fmaxf(gcnt[i], 1.0f);
    float z = bo[0];
#pragma unroll
    for (int j = 0; j < 4; ++j) z = fmaf(gsum[i * 4 + j] * inv, Wo[j], z);
    out[i] = 1.0f / (1.0f + expf(-z));
}

extern "C" void kernel_launch(void* const* d_in, const int* in_sizes, int n_in,
                              void* d_out, int out_size, void* d_ws, size_t ws_size,
                              hipStream_t stream) {
    const float* feat = (const float*)d_in[0];
    const int*   src  = (const int*)d_in[1];
    const int*   dst  = (const int*)d_in[2];
    const int*   gid  = (const int*)d_in[3];
    const float* W1   = (const float*)d_in[4];
    const float* b1   = (const float*)d_in[5];
    const float* W2   = (const float*)d_in[6];
    const float* b2   = (const float*)d_in[7];
    const float* Wo   = (const float*)d_in[8];
    const float* bo   = (const float*)d_in[9];
    float* out = (float*)d_out;

    const int n_nodes  = in_sizes[0] / 10;
    const int n_edges  = in_sizes[1];
    const int n_graphs = out_size;
    const int nbk_used = (n_nodes + (1 << BSHIFT) - 1) >> BSHIFT;

    unsigned int* ws32 = (unsigned int*)d_ws;
    const size_t PDW = (size_t)NBKT * CAP;
    const size_t n = (size_t)n_nodes;
    unsigned int*   pd     = ws32;
    unsigned short* ps     = (unsigned short*)ws32;        // aliases pd (time-muxed)
    unsigned int*   cs     = ws32 + PDW;                   // zeroed
    unsigned int*   cd     = cs + NBKT;                    // zeroed
    float*          gsum   = (float*)(cd + NBKT);          // zeroed
    float*          gcnt   = gsum + 4 * (size_t)n_graphs;  // zeroed
    float*          onorm  = gcnt + n_graphs;              // [n]
    unsigned int*   starts = (unsigned int*)(onorm + n);   // [NBKT*NBIN]
    unsigned int*   y1     = starts + (size_t)NBKT * NBIN; // [2n] dw, 8B aligned
    unsigned int*   y2     = y1 + 2 * n;                   // [n] dw
    u32x4*          part4  = (u32x4*)(y2 + n);             // [n] x 16B
    u32x2*          part2  = (u32x2*)part4;                // aliases part4 (time-muxed)

    (void)hipMemsetAsync(cs, 0, (2 * NBKT + 5 * (size_t)n_graphs) * sizeof(unsigned int),
                         stream);

    const int nchunk2 = (n_edges + CHUNK2 - 1) / CHUNK2;
    const int B = 256;

    k_part_src<<<nchunk2, PTH2, 0, stream>>>(src, ps, cs, n_edges);
    k_deg_src<<<nbk_used, 512, 0, stream>>>(ps, cs, onorm, n_nodes);
    k_part_dst<<<nchunk2, PTH2, 0, stream>>>(src, dst, pd, cd, n_edges);
    k_sort_dst<<<nbk_used, 512, 0, stream>>>(pd, cd, starts);
    k_node1<<<(n_nodes + B - 1) / B, B, 0, stream>>>(feat, W1, onorm, (uint2*)y1, n_nodes);
    k_agg1a<<<nbk_used, 1024, 0, stream>>>(pd, starts, (const uint2*)y1, part4, n_nodes);
    k_agg1b<<<nbk_used, 1024, 0, stream>>>(pd, cd, starts, (const uint2*)y1, part4, b1,
                                           W2, onorm, y2, n_nodes);
    k_agg2a<<<nbk_used, 1024, 0, stream>>>(pd, starts, y2, part2, n_nodes);
    k_agg2b<<<nbk_used, 1024, 0, stream>>>(pd, cd, starts, y2, part2, b2, gid, gsum,
                                           gcnt, n_nodes);
    k_final<<<(n_graphs + B - 1) / B, B, 0, stream>>>(gsum, gcnt, Wo, bo, out, n_graphs);
}

// Round 7
// 600.471 us; speedup vs baseline: 1.9092x; 1.0666x over previous
//
#include <hip/hip_runtime.h>
#include <hip/hip_fp16.h>
#include <math.h>

// ---------------------------------------------------------------------------
// R12b: resubmission of R12 (previous bench died to container infra failure
// before compiling/running; source audited for fault/hang risk -- none found).
// R12: fused partition + shfl-scan.
// R11 counters: k_part_dst = 90 us with WRITE 88 MB (amplification fixed) but
// only 1.7 TB/s and VALUBusy 52% -- issue/latency-bound in the 11-barrier
// ping-pong scan + LDS atomics. k_part_src has the same structure (~80 us).
// Fix: (1) fuse both partitions into one kernel (src read once from HBM,
// phase-D re-read is L2-hit; one launch), (2) wave-shfl scan (2 barriers,
// no ping-pong buffer) in k_part and k_sort_dst, (3) int4 edge loads.
// ps (34 MB) aliases starts..part4 (36.4 MB): dead after k_deg_src, which now
// runs before k_sort_dst.
//
// ws layout (dwords):
//   pd     [NBKT*CAP]
//   cs     [NBKT]  cd [NBKT]  gsum [4G]  gcnt [G]   (zeroed via memset)
//   onorm  [n]
//   starts [NBKT*2048]  <-- ps (ushort[NBKT*CAP]) aliases starts..part4
//   y1     [2n]   fp8x8 per node (8 B)
//   y2     [n]    fp8x4 per node (4 B)
//   part   [4n]   fp16x8 per node (16 B), reused as fp16x4 (8 B) for agg2
// ---------------------------------------------------------------------------

#define BSHIFT 10
#define BMASK  1023u
#define NBKT   1024
#define CAP    17408u
#define SRT    ((CAP + 511) / 512)
#define NBIN   2048
#define HSTAGE (CAP / 2)       // 8704 dwords = 34816 B LDS stage

#define PTH2   1024
#define EPT2   16
#define CHUNK2 (PTH2 * EPT2)   // 16384 edges / block
#define NW2    (PTH2 / 64)     // 16 waves

typedef float v2f __attribute__((ext_vector_type(2)));
typedef unsigned int u32x4 __attribute__((ext_vector_type(4)));
typedef unsigned int u32x2 __attribute__((ext_vector_type(2)));

template <bool HI>
__device__ inline v2f up8(unsigned int w) {
    return __builtin_amdgcn_cvt_pk_f32_fp8((int)w, HI);
}
__device__ inline unsigned int pk4(float a, float b, float c, float d) {
    int r = __builtin_amdgcn_cvt_pk_fp8_f32(a, b, 0, false);
    r = __builtin_amdgcn_cvt_pk_fp8_f32(c, d, r, true);
    return (unsigned int)r;
}
__device__ inline unsigned int pkh(float a, float b) {
    __half2 h = __floats2half2_rn(a, b);
    union { __half2 h; unsigned int u; } c; c.h = h; return c.u;
}
__device__ inline v2f uph(unsigned int u) {
    union { unsigned int u; __half2 h; } c; c.u = u;
    float2 f = __half22float2(c.h);
    v2f r; r.x = f.x; r.y = f.y; return r;
}
__device__ inline void acc8(float* acc, uint2 v) {
    v2f f0 = up8<false>(v.x);
    v2f f1 = up8<true>(v.x);
    v2f f2 = up8<false>(v.y);
    v2f f3 = up8<true>(v.y);
    acc[0] += f0.x; acc[1] += f0.y; acc[2] += f1.x; acc[3] += f1.y;
    acc[4] += f2.x; acc[5] += f2.y; acc[6] += f3.x; acc[7] += f3.y;
}
__device__ inline void acc4(float* acc, unsigned int q) {
    v2f f0 = up8<false>(q);
    v2f f1 = up8<true>(q);
    acc[0] += f0.x; acc[1] += f0.y; acc[2] += f1.x; acc[3] += f1.y;
}

// inclusive block scan of one value/thread, 1024 threads (16 waves)
__device__ inline unsigned int scan1024(unsigned int v, unsigned int* wsum, int tid) {
    const int lane = tid & 63, wid = tid >> 6;
    unsigned int x = v;
#pragma unroll
    for (int o = 1; o < 64; o <<= 1) {
        unsigned int t = __shfl_up(x, o);
        if (lane >= o) x += t;
    }
    if (lane == 63) wsum[wid] = x;
    __syncthreads();
    if (wid == 0) {
        unsigned int y = (lane < NW2) ? wsum[lane] : 0u;
#pragma unroll
        for (int o = 1; o < NW2; o <<= 1) {
            unsigned int t = __shfl_up(y, o);
            if (lane >= o) y += t;
        }
        if (lane < NW2) wsum[lane] = y;
    }
    __syncthreads();
    return x + (wid ? wsum[wid - 1] : 0u);
}

// ---- fused partition: phase S (src keys -> ps) + phase D (payload -> pd) --
__global__ __launch_bounds__(PTH2, 8) void k_part(const int* __restrict__ src,
                                                  const int* __restrict__ dst,
                                                  unsigned short* __restrict__ ps,
                                                  unsigned int* __restrict__ pd,
                                                  unsigned int* __restrict__ cs,
                                                  unsigned int* __restrict__ cd,
                                                  int n_edges) {
    __shared__ unsigned int pin[NBKT];
    __shared__ unsigned int gaddr[NBKT];
    __shared__ unsigned int wsum[NW2];
    __shared__ unsigned int stageD[CHUNK2];            // 64 KB; ushort view for S
    unsigned short* stageS = (unsigned short*)stageD;
    const int tid = threadIdx.x;
    const int lane = tid & 63, wid = tid >> 6;
    const int e0 = blockIdx.x * CHUNK2;

    // ---------------- phase S: partition src keys (ushort) ----------------
    pin[tid] = 0;
    __syncthreads();
    unsigned int sv[EPT2];
    unsigned int rks[EPT2];
#pragma unroll
    for (int k4 = 0; k4 < EPT2 / 4; ++k4) {
        int e = e0 + (k4 * PTH2 + tid) * 4;
        if (e + 3 < n_edges) {
            int4 s4 = *(const int4*)(src + e);
            sv[k4 * 4 + 0] = (unsigned int)s4.x;
            sv[k4 * 4 + 1] = (unsigned int)s4.y;
            sv[k4 * 4 + 2] = (unsigned int)s4.z;
            sv[k4 * 4 + 3] = (unsigned int)s4.w;
        } else {
#pragma unroll
            for (int j = 0; j < 4; ++j)
                sv[k4 * 4 + j] = (e + j < n_edges) ? (unsigned int)src[e + j]
                                                   : 0xFFFFFFFFu;
        }
    }
#pragma unroll
    for (int k = 0; k < EPT2; ++k)
        if (sv[k] != 0xFFFFFFFFu) rks[k] = atomicAdd(&pin[sv[k] >> BSHIFT], 1u);
    __syncthreads();
    {
        unsigned int cnt = pin[tid];
        unsigned int incl = scan1024(cnt, wsum, tid);
        unsigned int gb = atomicAdd(&cs[tid], cnt);
        pin[tid] = incl;                    // own-slot overwrite, no race
        gaddr[tid] = gb - (incl - cnt);     // dest off for staged pos i: gaddr+i
    }
    __syncthreads();
#pragma unroll
    for (int k = 0; k < EPT2; ++k) {
        if (sv[k] != 0xFFFFFFFFu) {
            unsigned int b = sv[k] >> BSHIFT;
            unsigned int start = (b == 0) ? 0u : pin[b - 1];
            stageS[start + rks[k]] = (unsigned short)(sv[k] & BMASK);
        }
    }
    __syncthreads();
    for (int b = wid; b < NBKT; b += NW2) {
        unsigned int start = (b == 0) ? 0u : pin[b - 1];
        unsigned int end = pin[b];
        unsigned int ga = gaddr[b];
        for (unsigned int i = start + lane; i < end; i += 64) {
            unsigned int off = ga + i;       // wraps correctly in u32
            ps[(size_t)b * CAP + off] = stageS[i];
        }
    }
    __syncthreads();

    // ---------------- phase D: partition (src,dstlow) by dst bucket --------
    pin[tid] = 0;
    __syncthreads();
    unsigned int wv[EPT2];
    unsigned int rkd[EPT2];                 // (bucket<<20) | rank, or sentinel
#pragma unroll
    for (int k4 = 0; k4 < EPT2 / 4; ++k4) {
        int e = e0 + (k4 * PTH2 + tid) * 4;
        if (e + 3 < n_edges) {
            int4 d4 = *(const int4*)(dst + e);
            int4 s4 = *(const int4*)(src + e);   // L2-hit (phase S streamed it)
            unsigned int dd[4] = {(unsigned int)d4.x, (unsigned int)d4.y,
                                  (unsigned int)d4.z, (unsigned int)d4.w};
            unsigned int ss[4] = {(unsigned int)s4.x, (unsigned int)s4.y,
                                  (unsigned int)s4.z, (unsigned int)s4.w};
#pragma unroll
            for (int j = 0; j < 4; ++j) {
                unsigned int b = dd[j] >> BSHIFT;
                wv[k4 * 4 + j] = (ss[j] << BSHIFT) | (dd[j] & BMASK);
                unsigned int r = atomicAdd(&pin[b], 1u);
                rkd[k4 * 4 + j] = (b << 20) | r;
            }
        } else {
#pragma unroll
            for (int j = 0; j < 4; ++j) {
                if (e + j < n_edges) {
                    unsigned int d = (unsigned int)dst[e + j];
                    unsigned int s = (unsigned int)src[e + j];
                    unsigned int b = d >> BSHIFT;
                    wv[k4 * 4 + j] = (s << BSHIFT) | (d & BMASK);
                    unsigned int r = atomicAdd(&pin[b], 1u);
                    rkd[k4 * 4 + j] = (b << 20) | r;
                } else {
                    rkd[k4 * 4 + j] = 0xFFFFFFFFu;
                }
            }
        }
    }
    __syncthreads();
    {
        unsigned int cnt = pin[tid];
        unsigned int incl = scan1024(cnt, wsum, tid);
        unsigned int gb = atomicAdd(&cd[tid], cnt);
        pin[tid] = incl;
        gaddr[tid] = gb - (incl - cnt);
    }
    __syncthreads();
#pragma unroll
    for (int k = 0; k < EPT2; ++k) {
        if (rkd[k] != 0xFFFFFFFFu) {
            unsigned int b = rkd[k] >> 20;
            unsigned int start = (b == 0) ? 0u : pin[b - 1];
            stageD[start + (rkd[k] & 0xFFFFFu)] = wv[k];
        }
    }
    __syncthreads();
    for (int b = wid; b < NBKT; b += NW2) {
        unsigned int start = (b == 0) ? 0u : pin[b - 1];
        unsigned int end = pin[b];
        unsigned int ga = gaddr[b];
        for (unsigned int i = start + lane; i < end; i += 64) {
            unsigned int off = ga + i;
            pd[(size_t)b * CAP + off] = stageD[i];
        }
    }
}

// ---- out-degree histogram per src bucket -> onorm -------------------------
__global__ __launch_bounds__(512) void k_deg_src(const unsigned short* __restrict__ ps,
                                                 const unsigned int* __restrict__ cur,
                                                 float* __restrict__ onorm, int n_nodes) {
    __shared__ unsigned int cnt[1 << BSHIFT];
    const int b = blockIdx.x, tid = threadIdx.x;
    for (int i = tid; i < (1 << BSHIFT); i += 512) cnt[i] = 0;
    __syncthreads();
    const unsigned int n = cur[b];
    const unsigned int base = (unsigned int)b * CAP;
    const unsigned int nfull = n & ~4095u;
    for (unsigned int i0 = 0; i0 < nfull; i0 += 4096) {
        uint4 p = *(const uint4*)(ps + base + i0 + (unsigned int)tid * 8u);
        unsigned int w[4] = {p.x, p.y, p.z, p.w};
#pragma unroll
        for (int k = 0; k < 4; ++k) {
            atomicAdd(&cnt[w[k] & 0xFFFFu], 1u);
            atomicAdd(&cnt[w[k] >> 16], 1u);
        }
    }
    for (unsigned int i = nfull + tid; i < n; i += 512) atomicAdd(&cnt[ps[base + i]], 1u);
    __syncthreads();
    for (int r = tid; r < (1 << BSHIFT); r += 512) {
        int node = (b << BSHIFT) + r;
        if (node < n_nodes) onorm[node] = rsqrtf(fmaxf((float)cnt[r], 1.0f));
    }
}

// ---- counting sort by (dst_low, src_tile), shfl-scan + LDS-staged out -----
// key = (dlow << 1) | tile, tile = bit19 of src (= bit29 of payload word).
__global__ __launch_bounds__(512) void k_sort_dst(unsigned int* __restrict__ pd,
                                                  const unsigned int* __restrict__ cur,
                                                  unsigned int* __restrict__ starts) {
    __shared__ unsigned int pin[NBIN];
    __shared__ unsigned int curs[NBIN];
    __shared__ unsigned int wsum[8];
    __shared__ unsigned int stage[HSTAGE];
    const int b = blockIdx.x, tid = threadIdx.x;
    const int lane = tid & 63, wid = tid >> 6;
    for (int i = tid; i < NBIN; i += 512) pin[i] = 0;
    __syncthreads();
    const unsigned int n = cur[b];
    const unsigned int base = (unsigned int)b * CAP;
    unsigned int rv[SRT];
#pragma unroll
    for (int k = 0; k < SRT; ++k) {
        unsigned int i = (unsigned int)k * 512u + (unsigned int)tid;
        rv[k] = 0xFFFFFFFFu;
        if (i < n) {
            rv[k] = pd[base + i];
            unsigned int key = ((rv[k] & BMASK) << 1) | ((rv[k] >> 29) & 1u);
            atomicAdd(&pin[key], 1u);
        }
    }
    __syncthreads();
    // scan: thread owns bins [4*tid, 4*tid+4)
    {
        unsigned int a0 = pin[4 * tid + 0], a1 = pin[4 * tid + 1];
        unsigned int a2 = pin[4 * tid + 2], a3 = pin[4 * tid + 3];
        unsigned int ts = a0 + a1 + a2 + a3;
        unsigned int x = ts;
#pragma unroll
        for (int o = 1; o < 64; o <<= 1) {
            unsigned int t = __shfl_up(x, o);
            if (lane >= o) x += t;
        }
        if (lane == 63) wsum[wid] = x;
        __syncthreads();
        if (wid == 0) {
            unsigned int y = (lane < 8) ? wsum[lane] : 0u;
#pragma unroll
            for (int o = 1; o < 8; o <<= 1) {
                unsigned int t = __shfl_up(y, o);
                if (lane >= o) y += t;
            }
            if (lane < 8) wsum[lane] = y;
        }
        __syncthreads();
        unsigned int ex = x - ts + (wid ? wsum[wid - 1] : 0u); // exclusive of bin 4tid
        unsigned int i0 = ex + a0, i1 = i0 + a1, i2 = i1 + a2, i3 = i2 + a3;
        pin[4 * tid + 0] = i0; pin[4 * tid + 1] = i1;
        pin[4 * tid + 2] = i2; pin[4 * tid + 3] = i3;
        curs[4 * tid + 0] = ex; curs[4 * tid + 1] = i0;
        curs[4 * tid + 2] = i1; curs[4 * tid + 3] = i2;
        unsigned int* sp = starts + ((size_t)b << 11) + 4 * tid;
        sp[0] = ex; sp[1] = i0; sp[2] = i1; sp[3] = i2;
    }
    __syncthreads();
    // final in-bucket positions, register-resident
    unsigned int pos[SRT];
#pragma unroll
    for (int k = 0; k < SRT; ++k) {
        pos[k] = 0xFFFFFFFFu;
        if (rv[k] != 0xFFFFFFFFu) {
            unsigned int key = ((rv[k] & BMASK) << 1) | ((rv[k] >> 29) & 1u);
            pos[k] = atomicAdd(&curs[key], 1u);
        }
    }
    __syncthreads();
    // pass 0: positions [0, HSTAGE)
#pragma unroll
    for (int k = 0; k < SRT; ++k)
        if (pos[k] < HSTAGE) stage[pos[k]] = rv[k];
    __syncthreads();
    const unsigned int lim0 = (n < HSTAGE) ? n : HSTAGE;
    for (unsigned int i = tid; i < lim0; i += 512) pd[base + i] = stage[i];
    __syncthreads();
    // pass 1: positions [HSTAGE, n)
#pragma unroll
    for (int k = 0; k < SRT; ++k)
        if (pos[k] != 0xFFFFFFFFu && pos[k] >= HSTAGE) stage[pos[k] - HSTAGE] = rv[k];
    __syncthreads();
    for (unsigned int i = HSTAGE + tid; i < n; i += 512) pd[base + i] = stage[i - HSTAGE];
}

// ---- y1 = fp8( (feat @ W1) * onorm )  (10 -> 8) ---------------------------
__global__ void k_node1(const float* __restrict__ feat, const float* __restrict__ W1,
                        const float* __restrict__ onorm, uint2* __restrict__ y1,
                        int n_nodes) {
    int i = blockIdx.x * blockDim.x + threadIdx.x;
    if (i >= n_nodes) return;
    float on = onorm[i];
    const float* fr = feat + (size_t)i * 10;
    float f[10];
#pragma unroll
    for (int k = 0; k < 10; ++k) f[k] = fr[k];
    float acc[8];
#pragma unroll
    for (int j = 0; j < 8; ++j) acc[j] = 0.0f;
#pragma unroll
    for (int k = 0; k < 10; ++k)
#pragma unroll
        for (int j = 0; j < 8; ++j) acc[j] = fmaf(f[k], W1[k * 8 + j], acc[j]);
    uint2 o;
    o.x = pk4(acc[0] * on, acc[1] * on, acc[2] * on, acc[3] * on);
    o.y = pk4(acc[4] * on, acc[5] * on, acc[6] * on, acc[7] * on);
    y1[i] = o;
}

// ---- layer1 agg, tile0: y1[0 .. 2^19) gathers only -> fp16 partial --------
__global__ __launch_bounds__(1024) void k_agg1a(const unsigned int* __restrict__ pd,
                                                const unsigned int* __restrict__ starts,
                                                const uint2* __restrict__ y,
                                                u32x4* __restrict__ part, int n_nodes) {
    const int b = blockIdx.x;
    const int r = threadIdx.x;
    const int node = (b << BSHIFT) + r;
    if (node >= n_nodes) return;
    const unsigned int base = (unsigned int)b * CAP;
    const unsigned int* st = starts + ((size_t)b << 11);
    unsigned int s = st[2 * r];
    unsigned int e = st[2 * r + 1];
    float acc[8];
#pragma unroll
    for (int j = 0; j < 8; ++j) acc[j] = 0.0f;
    unsigned int i = s;
    for (; i + 4 <= e; i += 4) {
        unsigned int w0 = pd[base + i + 0];
        unsigned int w1 = pd[base + i + 1];
        unsigned int w2 = pd[base + i + 2];
        unsigned int w3 = pd[base + i + 3];
        uint2 v0 = y[w0 >> BSHIFT];
        uint2 v1 = y[w1 >> BSHIFT];
        uint2 v2 = y[w2 >> BSHIFT];
        uint2 v3 = y[w3 >> BSHIFT];
        acc8(acc, v0); acc8(acc, v1); acc8(acc, v2); acc8(acc, v3);
    }
    for (; i < e; ++i) acc8(acc, y[pd[base + i] >> BSHIFT]);
    u32x4 p;
    p.x = pkh(acc[0], acc[1]);
    p.y = pkh(acc[2], acc[3]);
    p.z = pkh(acc[4], acc[5]);
    p.w = pkh(acc[6], acc[7]);
    __builtin_nontemporal_store(p, part + node);
}

// ---- layer1 agg, tile1 + partial add + fused node2 ------------------------
__global__ __launch_bounds__(1024) void k_agg1b(const unsigned int* __restrict__ pd,
                                                const unsigned int* __restrict__ cur,
                                                const unsigned int* __restrict__ starts,
                                                const uint2* __restrict__ y,
                                                const u32x4* __restrict__ part,
                                                const float* __restrict__ b1,
                                                const float* __restrict__ W2,
                                                const float* __restrict__ onorm,
                                                unsigned int* __restrict__ y2, int n_nodes) {
    const int b = blockIdx.x;
    const int r = threadIdx.x;
    const int node = (b << BSHIFT) + r;
    if (node >= n_nodes) return;
    const unsigned int base = (unsigned int)b * CAP;
    const unsigned int* st = starts + ((size_t)b << 11);
    unsigned int s0 = st[2 * r];
    unsigned int s = st[2 * r + 1];
    unsigned int e = (r == 1023) ? cur[b] : st[2 * r + 2];
    float acc[8];
#pragma unroll
    for (int j = 0; j < 8; ++j) acc[j] = 0.0f;
    unsigned int i = s;
    for (; i + 4 <= e; i += 4) {
        unsigned int w0 = pd[base + i + 0];
        unsigned int w1 = pd[base + i + 1];
        unsigned int w2 = pd[base + i + 2];
        unsigned int w3 = pd[base + i + 3];
        uint2 v0 = y[w0 >> BSHIFT];
        uint2 v1 = y[w1 >> BSHIFT];
        uint2 v2 = y[w2 >> BSHIFT];
        uint2 v3 = y[w3 >> BSHIFT];
        acc8(acc, v0); acc8(acc, v1); acc8(acc, v2); acc8(acc, v3);
    }
    for (; i < e; ++i) acc8(acc, y[pd[base + i] >> BSHIFT]);
    u32x4 p = __builtin_nontemporal_load(part + node);
    v2f q0 = uph(p.x), q1 = uph(p.y), q2 = uph(p.z), q3 = uph(p.w);
    acc[0] += q0.x; acc[1] += q0.y; acc[2] += q1.x; acc[3] += q1.y;
    acc[4] += q2.x; acc[5] += q2.y; acc[6] += q3.x; acc[7] += q3.y;
    float inn = rsqrtf(fmaxf((float)(e - s0), 1.0f));
    float h[8];
#pragma unroll
    for (int j = 0; j < 8; ++j) h[j] = fmaxf(fmaf(acc[j], inn, b1[j]), 0.0f);
    float z[4] = {0.0f, 0.0f, 0.0f, 0.0f};
#pragma unroll
    for (int k = 0; k < 8; ++k)
#pragma unroll
        for (int j = 0; j < 4; ++j) z[j] = fmaf(h[k], W2[k * 4 + j], z[j]);
    float on = onorm[node];
    y2[node] = pk4(z[0] * on, z[1] * on, z[2] * on, z[3] * on);
}

// ---- layer2 agg, tile0 -> fp16 partial ------------------------------------
__global__ __launch_bounds__(1024) void k_agg2a(const unsigned int* __restrict__ pd,
                                                const unsigned int* __restrict__ starts,
                                                const unsigned int* __restrict__ y,
                                                u32x2* __restrict__ part, int n_nodes) {
    const int b = blockIdx.x;
    const int r = threadIdx.x;
    const int node = (b << BSHIFT) + r;
    if (node >= n_nodes) return;
    const unsigned int base = (unsigned int)b * CAP;
    const unsigned int* st = starts + ((size_t)b << 11);
    unsigned int s = st[2 * r];
    unsigned int e = st[2 * r + 1];
    float acc[4] = {0.0f, 0.0f, 0.0f, 0.0f};
    unsigned int i = s;
    for (; i + 4 <= e; i += 4) {
        unsigned int w0 = pd[base + i + 0];
        unsigned int w1 = pd[base + i + 1];
        unsigned int w2 = pd[base + i + 2];
        unsigned int w3 = pd[base + i + 3];
        unsigned int q0 = y[w0 >> BSHIFT];
        unsigned int q1 = y[w1 >> BSHIFT];
        unsigned int q2 = y[w2 >> BSHIFT];
        unsigned int q3 = y[w3 >> BSHIFT];
        acc4(acc, q0); acc4(acc, q1); acc4(acc, q2); acc4(acc, q3);
    }
    for (; i < e; ++i) acc4(acc, y[pd[base + i] >> BSHIFT]);
    u32x2 p;
    p.x = pkh(acc[0], acc[1]);
    p.y = pkh(acc[2], acc[3]);
    __builtin_nontemporal_store(p, part + node);
}

// ---- layer2 agg, tile1 + partial add + fused graph pooling ----------------
__global__ __launch_bounds__(1024) void k_agg2b(const unsigned int* __restrict__ pd,
                                                const unsigned int* __restrict__ cur,
                                                const unsigned int* __restrict__ starts,
                                                const unsigned int* __restrict__ y,
                                                const u32x2* __restrict__ part,
                                                const float* __restrict__ b2,
                                                const int* __restrict__ gid,
                                                float* __restrict__ gsum,
                                                float* __restrict__ gcnt, int n_nodes) {
    const int b = blockIdx.x;
    const int r = threadIdx.x;
    const int node = (b << BSHIFT) + r;
    const int lane = threadIdx.x & 63;
    int g = -1;
    float v0 = 0.f, v1 = 0.f, v2 = 0.f, v3 = 0.f, c = 0.f;
    if (node < n_nodes) {
        const unsigned int base = (unsigned int)b * CAP;
        const unsigned int* st = starts + ((size_t)b << 11);
        unsigned int s0 = st[2 * r];
        unsigned int s = st[2 * r + 1];
        unsigned int e = (r == 1023) ? cur[b] : st[2 * r + 2];
        float acc[4] = {0.0f, 0.0f, 0.0f, 0.0f};
        unsigned int i = s;
        for (; i + 4 <= e; i += 4) {
            unsigned int w0 = pd[base + i + 0];
            unsigned int w1 = pd[base + i + 1];
            unsigned int w2 = pd[base + i + 2];
            unsigned int w3 = pd[base + i + 3];
            unsigned int q0 = y[w0 >> BSHIFT];
            unsigned int q1 = y[w1 >> BSHIFT];
            unsigned int q2 = y[w2 >> BSHIFT];
            unsigned int q3 = y[w3 >> BSHIFT];
            acc4(acc, q0); acc4(acc, q1); acc4(acc, q2); acc4(acc, q3);
        }
        for (; i < e; ++i) acc4(acc, y[pd[base + i] >> BSHIFT]);
        u32x2 p = __builtin_nontemporal_load(part + node);
        v2f p0 = uph(p.x), p1 = uph(p.y);
        acc[0] += p0.x; acc[1] += p0.y; acc[2] += p1.x; acc[3] += p1.y;
        float inn = rsqrtf(fmaxf((float)(e - s0), 1.0f));
        v0 = fmaxf(fmaf(acc[0], inn, b2[0]), 0.0f);
        v1 = fmaxf(fmaf(acc[1], inn, b2[1]), 0.0f);
        v2 = fmaxf(fmaf(acc[2], inn, b2[2]), 0.0f);
        v3 = fmaxf(fmaf(acc[3], inn, b2[3]), 0.0f);
        c = 1.0f;
        g = gid[node];
    }
#pragma unroll
    for (int sft = 1; sft < 64; sft <<= 1) {
        int go   = __shfl_down(g, sft);
        float t0 = __shfl_down(v0, sft);
        float t1 = __shfl_down(v1, sft);
        float t2 = __shfl_down(v2, sft);
        float t3 = __shfl_down(v3, sft);
        float tc = __shfl_down(c, sft);
        if (lane + sft < 64 && go == g) {
            v0 += t0; v1 += t1; v2 += t2; v3 += t3; c += tc;
        }
    }
    int gp = __shfl_up(g, 1);
    bool head = (lane == 0) || (gp != g);
    if (g >= 0 && head) {
        unsafeAtomicAdd(&gsum[g * 4 + 0], v0);
        unsafeAtomicAdd(&gsum[g * 4 + 1], v1);
        unsafeAtomicAdd(&gsum[g * 4 + 2], v2);
        unsafeAtomicAdd(&gsum[g * 4 + 3], v3);
        unsafeAtomicAdd(&gcnt[g], c);
    }
}

__global__ void k_final(const float* __restrict__ gsum, const float* __restrict__ gcnt,
                        const float* __restrict__ Wo, const float* __restrict__ bo,
                        float* __restrict__ out, int n_graphs) {
    int i = blockIdx.x * blockDim.x + threadIdx.x;
    if (i >= n_graphs) return;
    float inv = 1.0f / fmaxf(gcnt[i], 1.0f);
    float z = bo[0];
#pragma unroll
    for (int j = 0; j < 4; ++j) z = fmaf(gsum[i * 4 + j] * inv, Wo[j], z);
    out[i] = 1.0f / (1.0f + expf(-z));
}

extern "C" void kernel_launch(void* const* d_in, const int* in_sizes, int n_in,
                              void* d_out, int out_size, void* d_ws, size_t ws_size,
                              hipStream_t stream) {
    const float* feat = (const float*)d_in[0];
    const int*   src  = (const int*)d_in[1];
    const int*   dst  = (const int*)d_in[2];
    const int*   gid  = (const int*)d_in[3];
    const float* W1   = (const float*)d_in[4];
    const float* b1   = (const float*)d_in[5];
    const float* W2   = (const float*)d_in[6];
    const float* b2   = (const float*)d_in[7];
    const float* Wo   = (const float*)d_in[8];
    const float* bo   = (const float*)d_in[9];
    float* out = (float*)d_out;

    const int n_nodes  = in_sizes[0] / 10;
    const int n_edges  = in_sizes[1];
    const int n_graphs = out_size;
    const int nbk_used = (n_nodes + (1 << BSHIFT) - 1) >> BSHIFT;

    unsigned int* ws32 = (unsigned int*)d_ws;
    const size_t PDW = (size_t)NBKT * CAP;
    const size_t n = (size_t)n_nodes;
    unsigned int*   pd     = ws32;
    unsigned int*   cs     = ws32 + PDW;                   // zeroed
    unsigned int*   cd     = cs + NBKT;                    // zeroed
    float*          gsum   = (float*)(cd + NBKT);          // zeroed
    float*          gcnt   = gsum + 4 * (size_t)n_graphs;  // zeroed
    float*          onorm  = gcnt + n_graphs;              // [n]
    unsigned int*   starts = (unsigned int*)(onorm + n);   // [NBKT*NBIN]
    unsigned short* ps     = (unsigned short*)starts;      // [NBKT*CAP] ushort,
                                                           // aliases starts..part4
                                                           // (dead after k_deg_src)
    unsigned int*   y1     = starts + (size_t)NBKT * NBIN; // [2n] dw, 8B aligned
    unsigned int*   y2     = y1 + 2 * n;                   // [n] dw
    u32x4*          part4  = (u32x4*)(y2 + n);             // [n] x 16B
    u32x2*          part2  = (u32x2*)part4;                // aliases part4 (time-muxed)

    (void)hipMemsetAsync(cs, 0, (2 * NBKT + 5 * (size_t)n_graphs) * sizeof(unsigned int),
                         stream);

    const int nchunk2 = (n_edges + CHUNK2 - 1) / CHUNK2;
    const int B = 256;

    k_part<<<nchunk2, PTH2, 0, stream>>>(src, dst, ps, pd, cs, cd, n_edges);
    k_deg_src<<<nbk_used, 512, 0, stream>>>(ps, cs, onorm, n_nodes);
    k_sort_dst<<<nbk_used, 512, 0, stream>>>(pd, cd, starts);
    k_node1<<<(n_nodes + B - 1) / B, B, 0, stream>>>(feat, W1, onorm, (uint2*)y1, n_nodes);
    k_agg1a<<<nbk_used, 1024, 0, stream>>>(pd, starts, (const uint2*)y1, part4, n_nodes);
    k_agg1b<<<nbk_used, 1024, 0, stream>>>(pd, cd, starts, (const uint2*)y1, part4, b1,
                                           W2, onorm, y2, n_nodes);
    k_agg2a<<<nbk_used, 1024, 0, stream>>>(pd, starts, y2, part2, n_nodes);
    k_agg2b<<<nbk_used, 1024, 0, stream>>>(pd, cd, starts, y2, part2, b2, gid, gsum,
                                           gcnt, n_nodes);
    k_final<<<(n_graphs + B - 1) / B, B, 0, stream>>>(gsum, gcnt, Wo, bo, out, n_graphs);
}

// Round 8
// 569.891 us; speedup vs baseline: 2.0117x; 1.0537x over previous
//
#include <hip/hip_runtime.h>
#include <hip/hip_fp16.h>
#include <math.h>

// ---------------------------------------------------------------------------
// R13: quarter-wave write-out in k_part.
// R12b counters: k_part = 143 us, VALUBusy 62%, 1.6 TB/s (not BW-bound).
// Instruction audit: the per-bucket WAVE write-out is ~29M of ~109M wave
// instructions -- avg bucket load is ~16 elements, so a 64-lane wave runs
// each bucket's loop with 48-56 lanes idle. Fix: 16-lane groups (64 groups/
// block) -> 16 bucket-iterations/wave instead of 64, idle-lane waste ~4x
// down. Everything else unchanged from R12b.
//
// ws layout (dwords):
//   pd     [NBKT*CAP]
//   cs     [NBKT]  cd [NBKT]  gsum [4G]  gcnt [G]   (zeroed via memset)
//   onorm  [n]
//   starts [NBKT*2048]  <-- ps (ushort[NBKT*CAP]) aliases starts..part4
//   y1     [2n]   fp8x8 per node (8 B)
//   y2     [n]    fp8x4 per node (4 B)
//   part   [4n]   fp16x8 per node (16 B), reused as fp16x4 (8 B) for agg2
// ---------------------------------------------------------------------------

#define BSHIFT 10
#define BMASK  1023u
#define NBKT   1024
#define CAP    17408u
#define SRT    ((CAP + 511) / 512)
#define NBIN   2048
#define HSTAGE (CAP / 2)       // 8704 dwords = 34816 B LDS stage

#define PTH2   1024
#define EPT2   16
#define CHUNK2 (PTH2 * EPT2)   // 16384 edges / block
#define NW2    (PTH2 / 64)     // 16 waves

typedef float v2f __attribute__((ext_vector_type(2)));
typedef unsigned int u32x4 __attribute__((ext_vector_type(4)));
typedef unsigned int u32x2 __attribute__((ext_vector_type(2)));

template <bool HI>
__device__ inline v2f up8(unsigned int w) {
    return __builtin_amdgcn_cvt_pk_f32_fp8((int)w, HI);
}
__device__ inline unsigned int pk4(float a, float b, float c, float d) {
    int r = __builtin_amdgcn_cvt_pk_fp8_f32(a, b, 0, false);
    r = __builtin_amdgcn_cvt_pk_fp8_f32(c, d, r, true);
    return (unsigned int)r;
}
__device__ inline unsigned int pkh(float a, float b) {
    __half2 h = __floats2half2_rn(a, b);
    union { __half2 h; unsigned int u; } c; c.h = h; return c.u;
}
__device__ inline v2f uph(unsigned int u) {
    union { unsigned int u; __half2 h; } c; c.u = u;
    float2 f = __half22float2(c.h);
    v2f r; r.x = f.x; r.y = f.y; return r;
}
__device__ inline void acc8(float* acc, uint2 v) {
    v2f f0 = up8<false>(v.x);
    v2f f1 = up8<true>(v.x);
    v2f f2 = up8<false>(v.y);
    v2f f3 = up8<true>(v.y);
    acc[0] += f0.x; acc[1] += f0.y; acc[2] += f1.x; acc[3] += f1.y;
    acc[4] += f2.x; acc[5] += f2.y; acc[6] += f3.x; acc[7] += f3.y;
}
__device__ inline void acc4(float* acc, unsigned int q) {
    v2f f0 = up8<false>(q);
    v2f f1 = up8<true>(q);
    acc[0] += f0.x; acc[1] += f0.y; acc[2] += f1.x; acc[3] += f1.y;
}

// inclusive block scan of one value/thread, 1024 threads (16 waves)
__device__ inline unsigned int scan1024(unsigned int v, unsigned int* wsum, int tid) {
    const int lane = tid & 63, wid = tid >> 6;
    unsigned int x = v;
#pragma unroll
    for (int o = 1; o < 64; o <<= 1) {
        unsigned int t = __shfl_up(x, o);
        if (lane >= o) x += t;
    }
    if (lane == 63) wsum[wid] = x;
    __syncthreads();
    if (wid == 0) {
        unsigned int y = (lane < NW2) ? wsum[lane] : 0u;
#pragma unroll
        for (int o = 1; o < NW2; o <<= 1) {
            unsigned int t = __shfl_up(y, o);
            if (lane >= o) y += t;
        }
        if (lane < NW2) wsum[lane] = y;
    }
    __syncthreads();
    return x + (wid ? wsum[wid - 1] : 0u);
}

// ---- fused partition: phase S (src keys -> ps) + phase D (payload -> pd) --
__global__ __launch_bounds__(PTH2, 8) void k_part(const int* __restrict__ src,
                                                  const int* __restrict__ dst,
                                                  unsigned short* __restrict__ ps,
                                                  unsigned int* __restrict__ pd,
                                                  unsigned int* __restrict__ cs,
                                                  unsigned int* __restrict__ cd,
                                                  int n_edges) {
    __shared__ unsigned int pin[NBKT];
    __shared__ unsigned int gaddr[NBKT];
    __shared__ unsigned int wsum[NW2];
    __shared__ unsigned int stageD[CHUNK2];            // 64 KB; ushort view for S
    unsigned short* stageS = (unsigned short*)stageD;
    const int tid = threadIdx.x;
    const int qg = tid >> 4, ql = tid & 15;            // 64 quarter-groups of 16
    const int e0 = blockIdx.x * CHUNK2;

    // ---------------- phase S: partition src keys (ushort) ----------------
    pin[tid] = 0;
    __syncthreads();
    unsigned int sv[EPT2];
    unsigned int rks[EPT2];
#pragma unroll
    for (int k4 = 0; k4 < EPT2 / 4; ++k4) {
        int e = e0 + (k4 * PTH2 + tid) * 4;
        if (e + 3 < n_edges) {
            int4 s4 = *(const int4*)(src + e);
            sv[k4 * 4 + 0] = (unsigned int)s4.x;
            sv[k4 * 4 + 1] = (unsigned int)s4.y;
            sv[k4 * 4 + 2] = (unsigned int)s4.z;
            sv[k4 * 4 + 3] = (unsigned int)s4.w;
        } else {
#pragma unroll
            for (int j = 0; j < 4; ++j)
                sv[k4 * 4 + j] = (e + j < n_edges) ? (unsigned int)src[e + j]
                                                   : 0xFFFFFFFFu;
        }
    }
#pragma unroll
    for (int k = 0; k < EPT2; ++k)
        if (sv[k] != 0xFFFFFFFFu) rks[k] = atomicAdd(&pin[sv[k] >> BSHIFT], 1u);
    __syncthreads();
    {
        unsigned int cnt = pin[tid];
        unsigned int incl = scan1024(cnt, wsum, tid);
        unsigned int gb = atomicAdd(&cs[tid], cnt);
        pin[tid] = incl;                    // own-slot overwrite, no race
        gaddr[tid] = gb - (incl - cnt);     // dest off for staged pos i: gaddr+i
    }
    __syncthreads();
#pragma unroll
    for (int k = 0; k < EPT2; ++k) {
        if (sv[k] != 0xFFFFFFFFu) {
            unsigned int b = sv[k] >> BSHIFT;
            unsigned int start = (b == 0) ? 0u : pin[b - 1];
            stageS[start + rks[k]] = (unsigned short)(sv[k] & BMASK);
        }
    }
    __syncthreads();
    for (int b = qg; b < NBKT; b += 64) {
        unsigned int start = (b == 0) ? 0u : pin[b - 1];
        unsigned int end = pin[b];
        unsigned int ga = gaddr[b];
        for (unsigned int i = start + ql; i < end; i += 16) {
            unsigned int off = ga + i;       // wraps correctly in u32
            ps[(size_t)b * CAP + off] = stageS[i];
        }
    }
    __syncthreads();

    // ---------------- phase D: partition (src,dstlow) by dst bucket --------
    pin[tid] = 0;
    __syncthreads();
    unsigned int wv[EPT2];
    unsigned int rkd[EPT2];                 // (bucket<<20) | rank, or sentinel
#pragma unroll
    for (int k4 = 0; k4 < EPT2 / 4; ++k4) {
        int e = e0 + (k4 * PTH2 + tid) * 4;
        if (e + 3 < n_edges) {
            int4 d4 = *(const int4*)(dst + e);
            int4 s4 = *(const int4*)(src + e);   // L2-hit (phase S streamed it)
            unsigned int dd[4] = {(unsigned int)d4.x, (unsigned int)d4.y,
                                  (unsigned int)d4.z, (unsigned int)d4.w};
            unsigned int ss[4] = {(unsigned int)s4.x, (unsigned int)s4.y,
                                  (unsigned int)s4.z, (unsigned int)s4.w};
#pragma unroll
            for (int j = 0; j < 4; ++j) {
                unsigned int b = dd[j] >> BSHIFT;
                wv[k4 * 4 + j] = (ss[j] << BSHIFT) | (dd[j] & BMASK);
                unsigned int r = atomicAdd(&pin[b], 1u);
                rkd[k4 * 4 + j] = (b << 20) | r;
            }
        } else {
#pragma unroll
            for (int j = 0; j < 4; ++j) {
                if (e + j < n_edges) {
                    unsigned int d = (unsigned int)dst[e + j];
                    unsigned int s = (unsigned int)src[e + j];
                    unsigned int b = d >> BSHIFT;
                    wv[k4 * 4 + j] = (s << BSHIFT) | (d & BMASK);
                    unsigned int r = atomicAdd(&pin[b], 1u);
                    rkd[k4 * 4 + j] = (b << 20) | r;
                } else {
                    rkd[k4 * 4 + j] = 0xFFFFFFFFu;
                }
            }
        }
    }
    __syncthreads();
    {
        unsigned int cnt = pin[tid];
        unsigned int incl = scan1024(cnt, wsum, tid);
        unsigned int gb = atomicAdd(&cd[tid], cnt);
        pin[tid] = incl;
        gaddr[tid] = gb - (incl - cnt);
    }
    __syncthreads();
#pragma unroll
    for (int k = 0; k < EPT2; ++k) {
        if (rkd[k] != 0xFFFFFFFFu) {
            unsigned int b = rkd[k] >> 20;
            unsigned int start = (b == 0) ? 0u : pin[b - 1];
            stageD[start + (rkd[k] & 0xFFFFFu)] = wv[k];
        }
    }
    __syncthreads();
    for (int b = qg; b < NBKT; b += 64) {
        unsigned int start = (b == 0) ? 0u : pin[b - 1];
        unsigned int end = pin[b];
        unsigned int ga = gaddr[b];
        for (unsigned int i = start + ql; i < end; i += 16) {
            unsigned int off = ga + i;
            pd[(size_t)b * CAP + off] = stageD[i];
        }
    }
}

// ---- out-degree histogram per src bucket -> onorm -------------------------
__global__ __launch_bounds__(512) void k_deg_src(const unsigned short* __restrict__ ps,
                                                 const unsigned int* __restrict__ cur,
                                                 float* __restrict__ onorm, int n_nodes) {
    __shared__ unsigned int cnt[1 << BSHIFT];
    const int b = blockIdx.x, tid = threadIdx.x;
    for (int i = tid; i < (1 << BSHIFT); i += 512) cnt[i] = 0;
    __syncthreads();
    const unsigned int n = cur[b];
    const unsigned int base = (unsigned int)b * CAP;
    const unsigned int nfull = n & ~4095u;
    for (unsigned int i0 = 0; i0 < nfull; i0 += 4096) {
        uint4 p = *(const uint4*)(ps + base + i0 + (unsigned int)tid * 8u);
        unsigned int w[4] = {p.x, p.y, p.z, p.w};
#pragma unroll
        for (int k = 0; k < 4; ++k) {
            atomicAdd(&cnt[w[k] & 0xFFFFu], 1u);
            atomicAdd(&cnt[w[k] >> 16], 1u);
        }
    }
    for (unsigned int i = nfull + tid; i < n; i += 512) atomicAdd(&cnt[ps[base + i]], 1u);
    __syncthreads();
    for (int r = tid; r < (1 << BSHIFT); r += 512) {
        int node = (b << BSHIFT) + r;
        if (node < n_nodes) onorm[node] = rsqrtf(fmaxf((float)cnt[r], 1.0f));
    }
}

// ---- counting sort by (dst_low, src_tile), shfl-scan + LDS-staged out -----
// key = (dlow << 1) | tile, tile = bit19 of src (= bit29 of payload word).
__global__ __launch_bounds__(512) void k_sort_dst(unsigned int* __restrict__ pd,
                                                  const unsigned int* __restrict__ cur,
                                                  unsigned int* __restrict__ starts) {
    __shared__ unsigned int pin[NBIN];
    __shared__ unsigned int curs[NBIN];
    __shared__ unsigned int wsum[8];
    __shared__ unsigned int stage[HSTAGE];
    const int b = blockIdx.x, tid = threadIdx.x;
    const int lane = tid & 63, wid = tid >> 6;
    for (int i = tid; i < NBIN; i += 512) pin[i] = 0;
    __syncthreads();
    const unsigned int n = cur[b];
    const unsigned int base = (unsigned int)b * CAP;
    unsigned int rv[SRT];
#pragma unroll
    for (int k = 0; k < SRT; ++k) {
        unsigned int i = (unsigned int)k * 512u + (unsigned int)tid;
        rv[k] = 0xFFFFFFFFu;
        if (i < n) {
            rv[k] = pd[base + i];
            unsigned int key = ((rv[k] & BMASK) << 1) | ((rv[k] >> 29) & 1u);
            atomicAdd(&pin[key], 1u);
        }
    }
    __syncthreads();
    // scan: thread owns bins [4*tid, 4*tid+4)
    {
        unsigned int a0 = pin[4 * tid + 0], a1 = pin[4 * tid + 1];
        unsigned int a2 = pin[4 * tid + 2], a3 = pin[4 * tid + 3];
        unsigned int ts = a0 + a1 + a2 + a3;
        unsigned int x = ts;
#pragma unroll
        for (int o = 1; o < 64; o <<= 1) {
            unsigned int t = __shfl_up(x, o);
            if (lane >= o) x += t;
        }
        if (lane == 63) wsum[wid] = x;
        __syncthreads();
        if (wid == 0) {
            unsigned int y = (lane < 8) ? wsum[lane] : 0u;
#pragma unroll
            for (int o = 1; o < 8; o <<= 1) {
                unsigned int t = __shfl_up(y, o);
                if (lane >= o) y += t;
            }
            if (lane < 8) wsum[lane] = y;
        }
        __syncthreads();
        unsigned int ex = x - ts + (wid ? wsum[wid - 1] : 0u); // exclusive of bin 4tid
        unsigned int i0 = ex + a0, i1 = i0 + a1, i2 = i1 + a2, i3 = i2 + a3;
        pin[4 * tid + 0] = i0; pin[4 * tid + 1] = i1;
        pin[4 * tid + 2] = i2; pin[4 * tid + 3] = i3;
        curs[4 * tid + 0] = ex; curs[4 * tid + 1] = i0;
        curs[4 * tid + 2] = i1; curs[4 * tid + 3] = i2;
        unsigned int* sp = starts + ((size_t)b << 11) + 4 * tid;
        sp[0] = ex; sp[1] = i0; sp[2] = i1; sp[3] = i2;
    }
    __syncthreads();
    // final in-bucket positions, register-resident
    unsigned int pos[SRT];
#pragma unroll
    for (int k = 0; k < SRT; ++k) {
        pos[k] = 0xFFFFFFFFu;
        if (rv[k] != 0xFFFFFFFFu) {
            unsigned int key = ((rv[k] & BMASK) << 1) | ((rv[k] >> 29) & 1u);
            pos[k] = atomicAdd(&curs[key], 1u);
        }
    }
    __syncthreads();
    // pass 0: positions [0, HSTAGE)
#pragma unroll
    for (int k = 0; k < SRT; ++k)
        if (pos[k] < HSTAGE) stage[pos[k]] = rv[k];
    __syncthreads();
    const unsigned int lim0 = (n < HSTAGE) ? n : HSTAGE;
    for (unsigned int i = tid; i < lim0; i += 512) pd[base + i] = stage[i];
    __syncthreads();
    // pass 1: positions [HSTAGE, n)
#pragma unroll
    for (int k = 0; k < SRT; ++k)
        if (pos[k] != 0xFFFFFFFFu && pos[k] >= HSTAGE) stage[pos[k] - HSTAGE] = rv[k];
    __syncthreads();
    for (unsigned int i = HSTAGE + tid; i < n; i += 512) pd[base + i] = stage[i - HSTAGE];
}

// ---- y1 = fp8( (feat @ W1) * onorm )  (10 -> 8) ---------------------------
__global__ void k_node1(const float* __restrict__ feat, const float* __restrict__ W1,
                        const float* __restrict__ onorm, uint2* __restrict__ y1,
                        int n_nodes) {
    int i = blockIdx.x * blockDim.x + threadIdx.x;
    if (i >= n_nodes) return;
    float on = onorm[i];
    const float* fr = feat + (size_t)i * 10;
    float f[10];
#pragma unroll
    for (int k = 0; k < 10; ++k) f[k] = fr[k];
    float acc[8];
#pragma unroll
    for (int j = 0; j < 8; ++j) acc[j] = 0.0f;
#pragma unroll
    for (int k = 0; k < 10; ++k)
#pragma unroll
        for (int j = 0; j < 8; ++j) acc[j] = fmaf(f[k], W1[k * 8 + j], acc[j]);
    uint2 o;
    o.x = pk4(acc[0] * on, acc[1] * on, acc[2] * on, acc[3] * on);
    o.y = pk4(acc[4] * on, acc[5] * on, acc[6] * on, acc[7] * on);
    y1[i] = o;
}

// ---- layer1 agg, tile0: y1[0 .. 2^19) gathers only -> fp16 partial --------
__global__ __launch_bounds__(1024) void k_agg1a(const unsigned int* __restrict__ pd,
                                                const unsigned int* __restrict__ starts,
                                                const uint2* __restrict__ y,
                                                u32x4* __restrict__ part, int n_nodes) {
    const int b = blockIdx.x;
    const int r = threadIdx.x;
    const int node = (b << BSHIFT) + r;
    if (node >= n_nodes) return;
    const unsigned int base = (unsigned int)b * CAP;
    const unsigned int* st = starts + ((size_t)b << 11);
    unsigned int s = st[2 * r];
    unsigned int e = st[2 * r + 1];
    float acc[8];
#pragma unroll
    for (int j = 0; j < 8; ++j) acc[j] = 0.0f;
    unsigned int i = s;
    for (; i + 4 <= e; i += 4) {
        unsigned int w0 = pd[base + i + 0];
        unsigned int w1 = pd[base + i + 1];
        unsigned int w2 = pd[base + i + 2];
        unsigned int w3 = pd[base + i + 3];
        uint2 v0 = y[w0 >> BSHIFT];
        uint2 v1 = y[w1 >> BSHIFT];
        uint2 v2 = y[w2 >> BSHIFT];
        uint2 v3 = y[w3 >> BSHIFT];
        acc8(acc, v0); acc8(acc, v1); acc8(acc, v2); acc8(acc, v3);
    }
    for (; i < e; ++i) acc8(acc, y[pd[base + i] >> BSHIFT]);
    u32x4 p;
    p.x = pkh(acc[0], acc[1]);
    p.y = pkh(acc[2], acc[3]);
    p.z = pkh(acc[4], acc[5]);
    p.w = pkh(acc[6], acc[7]);
    __builtin_nontemporal_store(p, part + node);
}

// ---- layer1 agg, tile1 + partial add + fused node2 ------------------------
__global__ __launch_bounds__(1024) void k_agg1b(const unsigned int* __restrict__ pd,
                                                const unsigned int* __restrict__ cur,
                                                const unsigned int* __restrict__ starts,
                                                const uint2* __restrict__ y,
                                                const u32x4* __restrict__ part,
                                                const float* __restrict__ b1,
                                                const float* __restrict__ W2,
                                                const float* __restrict__ onorm,
                                                unsigned int* __restrict__ y2, int n_nodes) {
    const int b = blockIdx.x;
    const int r = threadIdx.x;
    const int node = (b << BSHIFT) + r;
    if (node >= n_nodes) return;
    const unsigned int base = (unsigned int)b * CAP;
    const unsigned int* st = starts + ((size_t)b << 11);
    unsigned int s0 = st[2 * r];
    unsigned int s = st[2 * r + 1];
    unsigned int e = (r == 1023) ? cur[b] : st[2 * r + 2];
    float acc[8];
#pragma unroll
    for (int j = 0; j < 8; ++j) acc[j] = 0.0f;
    unsigned int i = s;
    for (; i + 4 <= e; i += 4) {
        unsigned int w0 = pd[base + i + 0];
        unsigned int w1 = pd[base + i + 1];
        unsigned int w2 = pd[base + i + 2];
        unsigned int w3 = pd[base + i + 3];
        uint2 v0 = y[w0 >> BSHIFT];
        uint2 v1 = y[w1 >> BSHIFT];
        uint2 v2 = y[w2 >> BSHIFT];
        uint2 v3 = y[w3 >> BSHIFT];
        acc8(acc, v0); acc8(acc, v1); acc8(acc, v2); acc8(acc, v3);
    }
    for (; i < e; ++i) acc8(acc, y[pd[base + i] >> BSHIFT]);
    u32x4 p = __builtin_nontemporal_load(part + node);
    v2f q0 = uph(p.x), q1 = uph(p.y), q2 = uph(p.z), q3 = uph(p.w);
    acc[0] += q0.x; acc[1] += q0.y; acc[2] += q1.x; acc[3] += q1.y;
    acc[4] += q2.x; acc[5] += q2.y; acc[6] += q3.x; acc[7] += q3.y;
    float inn = rsqrtf(fmaxf((float)(e - s0), 1.0f));
    float h[8];
#pragma unroll
    for (int j = 0; j < 8; ++j) h[j] = fmaxf(fmaf(acc[j], inn, b1[j]), 0.0f);
    float z[4] = {0.0f, 0.0f, 0.0f, 0.0f};
#pragma unroll
    for (int k = 0; k < 8; ++k)
#pragma unroll
        for (int j = 0; j < 4; ++j) z[j] = fmaf(h[k], W2[k * 4 + j], z[j]);
    float on = onorm[node];
    y2[node] = pk4(z[0] * on, z[1] * on, z[2] * on, z[3] * on);
}

// ---- layer2 agg, tile0 -> fp16 partial ------------------------------------
__global__ __launch_bounds__(1024) void k_agg2a(const unsigned int* __restrict__ pd,
                                                const unsigned int* __restrict__ starts,
                                                const unsigned int* __restrict__ y,
                                                u32x2* __restrict__ part, int n_nodes) {
    const int b = blockIdx.x;
    const int r = threadIdx.x;
    const int node = (b << BSHIFT) + r;
    if (node >= n_nodes) return;
    const unsigned int base = (unsigned int)b * CAP;
    const unsigned int* st = starts + ((size_t)b << 11);
    unsigned int s = st[2 * r];
    unsigned int e = st[2 * r + 1];
    float acc[4] = {0.0f, 0.0f, 0.0f, 0.0f};
    unsigned int i = s;
    for (; i + 4 <= e; i += 4) {
        unsigned int w0 = pd[base + i + 0];
        unsigned int w1 = pd[base + i + 1];
        unsigned int w2 = pd[base + i + 2];
        unsigned int w3 = pd[base + i + 3];
        unsigned int q0 = y[w0 >> BSHIFT];
        unsigned int q1 = y[w1 >> BSHIFT];
        unsigned int q2 = y[w2 >> BSHIFT];
        unsigned int q3 = y[w3 >> BSHIFT];
        acc4(acc, q0); acc4(acc, q1); acc4(acc, q2); acc4(acc, q3);
    }
    for (; i < e; ++i) acc4(acc, y[pd[base + i] >> BSHIFT]);
    u32x2 p;
    p.x = pkh(acc[0], acc[1]);
    p.y = pkh(acc[2], acc[3]);
    __builtin_nontemporal_store(p, part + node);
}

// ---- layer2 agg, tile1 + partial add + fused graph pooling ----------------
__global__ __launch_bounds__(1024) void k_agg2b(const unsigned int* __restrict__ pd,
                                                const unsigned int* __restrict__ cur,
                                                const unsigned int* __restrict__ starts,
                                                const unsigned int* __restrict__ y,
                                                const u32x2* __restrict__ part,
                                                const float* __restrict__ b2,
                                                const int* __restrict__ gid,
                                                float* __restrict__ gsum,
                                                float* __restrict__ gcnt, int n_nodes) {
    const int b = blockIdx.x;
    const int r = threadIdx.x;
    const int node = (b << BSHIFT) + r;
    const int lane = threadIdx.x & 63;
    int g = -1;
    float v0 = 0.f, v1 = 0.f, v2 = 0.f, v3 = 0.f, c = 0.f;
    if (node < n_nodes) {
        const unsigned int base = (unsigned int)b * CAP;
        const unsigned int* st = starts + ((size_t)b << 11);
        unsigned int s0 = st[2 * r];
        unsigned int s = st[2 * r + 1];
        unsigned int e = (r == 1023) ? cur[b] : st[2 * r + 2];
        float acc[4] = {0.0f, 0.0f, 0.0f, 0.0f};
        unsigned int i = s;
        for (; i + 4 <= e; i += 4) {
            unsigned int w0 = pd[base + i + 0];
            unsigned int w1 = pd[base + i + 1];
            unsigned int w2 = pd[base + i + 2];
            unsigned int w3 = pd[base + i + 3];
            unsigned int q0 = y[w0 >> BSHIFT];
            unsigned int q1 = y[w1 >> BSHIFT];
            unsigned int q2 = y[w2 >> BSHIFT];
            unsigned int q3 = y[w3 >> BSHIFT];
            acc4(acc, q0); acc4(acc, q1); acc4(acc, q2); acc4(acc, q3);
        }
        for (; i < e; ++i) acc4(acc, y[pd[base + i] >> BSHIFT]);
        u32x2 p = __builtin_nontemporal_load(part + node);
        v2f p0 = uph(p.x), p1 = uph(p.y);
        acc[0] += p0.x; acc[1] += p0.y; acc[2] += p1.x; acc[3] += p1.y;
        float inn = rsqrtf(fmaxf((float)(e - s0), 1.0f));
        v0 = fmaxf(fmaf(acc[0], inn, b2[0]), 0.0f);
        v1 = fmaxf(fmaf(acc[1], inn, b2[1]), 0.0f);
        v2 = fmaxf(fmaf(acc[2], inn, b2[2]), 0.0f);
        v3 = fmaxf(fmaf(acc[3], inn, b2[3]), 0.0f);
        c = 1.0f;
        g = gid[node];
    }
#pragma unroll
    for (int sft = 1; sft < 64; sft <<= 1) {
        int go   = __shfl_down(g, sft);
        float t0 = __shfl_down(v0, sft);
        float t1 = __shfl_down(v1, sft);
        float t2 = __shfl_down(v2, sft);
        float t3 = __shfl_down(v3, sft);
        float tc = __shfl_down(c, sft);
        if (lane + sft < 64 && go == g) {
            v0 += t0; v1 += t1; v2 += t2; v3 += t3; c += tc;
        }
    }
    int gp = __shfl_up(g, 1);
    bool head = (lane == 0) || (gp != g);
    if (g >= 0 && head) {
        unsafeAtomicAdd(&gsum[g * 4 + 0], v0);
        unsafeAtomicAdd(&gsum[g * 4 + 1], v1);
        unsafeAtomicAdd(&gsum[g * 4 + 2], v2);
        unsafeAtomicAdd(&gsum[g * 4 + 3], v3);
        unsafeAtomicAdd(&gcnt[g], c);
    }
}

__global__ void k_final(const float* __restrict__ gsum, const float* __restrict__ gcnt,
                        const float* __restrict__ Wo, const float* __restrict__ bo,
                        float* __restrict__ out, int n_graphs) {
    int i = blockIdx.x * blockDim.x + threadIdx.x;
    if (i >= n_graphs) return;
    float inv = 1.0f / fmaxf(gcnt[i], 1.0f);
    float z = bo[0];
#pragma unroll
    for (int j = 0; j < 4; ++j) z = fmaf(gsum[i * 4 + j] * inv, Wo[j], z);
    out[i] = 1.0f / (1.0f + expf(-z));
}

extern "C" void kernel_launch(void* const* d_in, const int* in_sizes, int n_in,
                              void* d_out, int out_size, void* d_ws, size_t ws_size,
                              hipStream_t stream) {
    const float* feat = (const float*)d_in[0];
    const int*   src  = (const int*)d_in[1];
    const int*   dst  = (const int*)d_in[2];
    const int*   gid  = (const int*)d_in[3];
    const float* W1   = (const float*)d_in[4];
    const float* b1   = (const float*)d_in[5];
    const float* W2   = (const float*)d_in[6];
    const float* b2   = (const float*)d_in[7];
    const float* Wo   = (const float*)d_in[8];
    const float* bo   = (const float*)d_in[9];
    float* out = (float*)d_out;

    const int n_nodes  = in_sizes[0] / 10;
    const int n_edges  = in_sizes[1];
    const int n_graphs = out_size;
    const int nbk_used = (n_nodes + (1 << BSHIFT) - 1) >> BSHIFT;

    unsigned int* ws32 = (unsigned int*)d_ws;
    const size_t PDW = (size_t)NBKT * CAP;
    const size_t n = (size_t)n_nodes;
    unsigned int*   pd     = ws32;
    unsigned int*   cs     = ws32 + PDW;                   // zeroed
    unsigned int*   cd     = cs + NBKT;                    // zeroed
    float*          gsum   = (float*)(cd + NBKT);          // zeroed
    float*          gcnt   = gsum + 4 * (size_t)n_graphs;  // zeroed
    float*          onorm  = gcnt + n_graphs;              // [n]
    unsigned int*   starts = (unsigned int*)(onorm + n);   // [NBKT*NBIN]
    unsigned short* ps     = (unsigned short*)starts;      // [NBKT*CAP] ushort,
                                                           // aliases starts..part4
                                                           // (dead after k_deg_src)
    unsigned int*   y1     = starts + (size_t)NBKT * NBIN; // [2n] dw, 8B aligned
    unsigned int*   y2     = y1 + 2 * n;                   // [n] dw
    u32x4*          part4  = (u32x4*)(y2 + n);             // [n] x 16B
    u32x2*          part2  = (u32x2*)part4;                // aliases part4 (time-muxed)

    (void)hipMemsetAsync(cs, 0, (2 * NBKT + 5 * (size_t)n_graphs) * sizeof(unsigned int),
                         stream);

    const int nchunk2 = (n_edges + CHUNK2 - 1) / CHUNK2;
    const int B = 256;

    k_part<<<nchunk2, PTH2, 0, stream>>>(src, dst, ps, pd, cs, cd, n_edges);
    k_deg_src<<<nbk_used, 512, 0, stream>>>(ps, cs, onorm, n_nodes);
    k_sort_dst<<<nbk_used, 512, 0, stream>>>(pd, cd, starts);
    k_node1<<<(n_nodes + B - 1) / B, B, 0, stream>>>(feat, W1, onorm, (uint2*)y1, n_nodes);
    k_agg1a<<<nbk_used, 1024, 0, stream>>>(pd, starts, (const uint2*)y1, part4, n_nodes);
    k_agg1b<<<nbk_used, 1024, 0, stream>>>(pd, cd, starts, (const uint2*)y1, part4, b1,
                                           W2, onorm, y2, n_nodes);
    k_agg2a<<<nbk_used, 1024, 0, stream>>>(pd, starts, y2, part2, n_nodes);
    k_agg2b<<<nbk_used, 1024, 0, stream>>>(pd, cd, starts, y2, part2, b2, gid, gsum,
                                           gcnt, n_nodes);
    k_final<<<(n_graphs + B - 1) / B, B, 0, stream>>>(gsum, gcnt, Wo, bo, out, n_graphs);
}